// Round 1
// baseline (587.584 us; speedup 1.0000x reference)
//
#include <hip/hip_runtime.h>
#include <stdint.h>

typedef unsigned int u32;
typedef unsigned long long u64;

#define NBW 120
#define NBH 68
#define NTILES (NBW * NBH)       // 8160
#define NPTS 500000
#define EE 12500000              // N * K * K
#define SORT_CAP 2048

__device__ __forceinline__ int clampi(int v, int lo, int hi) {
    return v < lo ? lo : (v > hi ? hi : v);
}

__device__ __forceinline__ void tile_window(float x, float y, float r,
                                            int& x0, int& x1, int& y0, int& y1) {
    // matches jnp: clip(floor_divide(x - r, 16), 0, NBW) etc. (/16 and *0.0625f are both exact)
    x0 = clampi((int)floorf((x - r) * 0.0625f), 0, NBW);
    x1 = clampi((int)floorf((x + r) * 0.0625f) + 1, 0, NBW);
    y0 = clampi((int)floorf((y - r) * 0.0625f), 0, NBH);
    y1 = clampi((int)floorf((y + r) * 0.0625f) + 1, 0, NBH);
}

// monotone float -> u32 such that ascending u32 == DESCENDING float
__device__ __forceinline__ u32 depth_key(float d) {
    u32 fu = __float_as_uint(d);
    u32 asc = (fu & 0x80000000u) ? ~fu : (fu | 0x80000000u);
    return ~asc;
}
__device__ __forceinline__ float depth_unkey(u32 dk) {
    u32 asc = ~dk;
    u32 fu = (asc & 0x80000000u) ? (asc & 0x7FFFFFFFu) : ~asc;
    return __uint_as_float(fu);
}

__device__ __forceinline__ u64 combine_key(u32 dk, u32 pid) {
    return ((u64)dk << 19) | (u64)pid;   // pid < 2^19
}

__global__ void zero_counts_kernel(u32* __restrict__ counts) {
    int i = blockIdx.x * blockDim.x + threadIdx.x;
    if (i < NTILES) counts[i] = 0;
}

__global__ void hist_kernel(const float2* __restrict__ pos, const float* __restrict__ rad,
                            u32* __restrict__ counts) {
    int i = blockIdx.x * blockDim.x + threadIdx.x;
    if (i >= NPTS) return;
    float2 p = pos[i];
    float r = rad[i];
    int x0, x1, y0, y1;
    tile_window(p.x, p.y, r, x0, x1, y0, y1);
    for (int xi = x0; xi < x1; ++xi)
        for (int yi = y0; yi < y1; ++yi)
            atomicAdd(&counts[xi * NBH + yi], 1u);
}

__global__ __launch_bounds__(1024) void scan_kernel(const u32* __restrict__ counts,
                                                    u32* __restrict__ offsets,
                                                    u32* __restrict__ cursors,
                                                    float* __restrict__ out_count) {
    __shared__ u32 sA[1024], sB[1024];
    int t = threadIdx.x;
    int base = t * 8;
    u32 local[8];
    u32 sum = 0;
#pragma unroll
    for (int j = 0; j < 8; ++j) {
        u32 c = (base + j < NTILES) ? counts[base + j] : 0u;
        local[j] = c;
        sum += c;
    }
    sA[t] = sum;
    __syncthreads();
    u32* cur = sA;
    u32* nxt = sB;
    for (int off = 1; off < 1024; off <<= 1) {
        u32 v = cur[t];
        if (t >= off) v += cur[t - off];
        nxt[t] = v;
        __syncthreads();
        u32* tmp = cur; cur = nxt; nxt = tmp;
    }
    u32 run = cur[t] - sum;   // exclusive base for this thread's chunk
#pragma unroll
    for (int j = 0; j < 8; ++j) {
        int idx = base + j;
        if (idx < NTILES) {
            offsets[idx] = run;
            cursors[idx] = run;
            out_count[idx] = (float)run;
            run += local[j];
        }
    }
    if (t == 1023) offsets[NTILES] = cur[1023];   // total live entries
}

__global__ void scatter_kernel(const float2* __restrict__ pos, const float* __restrict__ rad,
                               const float* __restrict__ depth,
                               u32* __restrict__ cursors,
                               u32* __restrict__ stage_pid, u32* __restrict__ stage_key) {
    int i = blockIdx.x * blockDim.x + threadIdx.x;
    if (i >= NPTS) return;
    float2 p = pos[i];
    float r = rad[i];
    u32 dk = depth_key(depth[i]);
    int x0, x1, y0, y1;
    tile_window(p.x, p.y, r, x0, x1, y0, y1);
    for (int xi = x0; xi < x1; ++xi)
        for (int yi = y0; yi < y1; ++yi) {
            u32 slot = atomicAdd(&cursors[xi * NBH + yi], 1u);
            stage_pid[slot] = (u32)i;
            stage_key[slot] = dk;
        }
}

__global__ void fill_tail_kernel(const u32* __restrict__ total_ptr,
                                 float* __restrict__ out_idx, float* __restrict__ out_depth) {
    int t = blockIdx.x * blockDim.x + threadIdx.x;
    int i0 = t * 4;
    if (i0 >= EE) return;
    int total = (int)(*total_ptr);
    if (i0 >= total) {
        ((float4*)out_idx)[t]   = make_float4(-1.f, -1.f, -1.f, -1.f);
        ((float4*)out_depth)[t] = make_float4(0.f, 0.f, 0.f, 0.f);
    } else if (i0 + 4 > total) {
#pragma unroll
        for (int j = 0; j < 4; ++j) {
            int i = i0 + j;
            if (i >= total) { out_idx[i] = -1.f; out_depth[i] = 0.f; }
        }
    }
}

__global__ __launch_bounds__(256) void sort_kernel(const u32* __restrict__ offsets,
                                                   u32* __restrict__ stage_pid,
                                                   u32* __restrict__ stage_key,
                                                   float* __restrict__ out_idx,
                                                   float* __restrict__ out_depth) {
    __shared__ u64 skey[SORT_CAP];
    int t = blockIdx.x;
    u32 base = offsets[t];
    int cnt = (int)(offsets[t + 1] - base);
    if (cnt <= 0) return;

    int n = 1;
    while (n < cnt) n <<= 1;

    if (n <= SORT_CAP) {
        for (int i = threadIdx.x; i < n; i += 256) {
            u64 k;
            if (i < cnt) k = combine_key(stage_key[base + i], stage_pid[base + i]);
            else         k = ~0ull;
            skey[i] = k;
        }
        __syncthreads();
        for (int kk = 2; kk <= n; kk <<= 1) {
            for (int j = kk >> 1; j > 0; j >>= 1) {
                for (int i = threadIdx.x; i < n; i += 256) {
                    int ixj = i ^ j;
                    if (ixj > i) {
                        bool up = ((i & kk) == 0);
                        u64 a = skey[i], b = skey[ixj];
                        if ((a > b) == up) { skey[i] = b; skey[ixj] = a; }
                    }
                }
                __syncthreads();
            }
        }
        for (int i = threadIdx.x; i < cnt; i += 256) {
            u64 k = skey[i];
            u32 pid = (u32)(k & 0x7FFFFu);
            u32 dk  = (u32)(k >> 19);
            out_idx[base + i]   = (float)pid;
            out_depth[base + i] = depth_unkey(dk);
        }
    } else {
        // Paranoia fallback (statistically unreachable for this input):
        // odd-even transposition sort directly on the staged global arrays.
        for (int round = 0; round < cnt; ++round) {
            for (int i = (round & 1) + 2 * (int)threadIdx.x; i + 1 < cnt; i += 512) {
                u32 p0 = stage_pid[base + i], p1 = stage_pid[base + i + 1];
                u32 k0 = stage_key[base + i], k1 = stage_key[base + i + 1];
                if (combine_key(k0, p0) > combine_key(k1, p1)) {
                    stage_pid[base + i] = p1; stage_pid[base + i + 1] = p0;
                    stage_key[base + i] = k1; stage_key[base + i + 1] = k0;
                }
            }
            __syncthreads();
        }
        for (int i = threadIdx.x; i < cnt; i += 256) {
            u32 pid = stage_pid[base + i];
            u32 dk  = stage_key[base + i];
            out_idx[base + i]   = (float)pid;   // aliases stage_pid[base+i], same thread
            out_depth[base + i] = depth_unkey(dk);
        }
    }
}

extern "C" void kernel_launch(void* const* d_in, const int* in_sizes, int n_in,
                              void* d_out, int out_size, void* d_ws, size_t ws_size,
                              hipStream_t stream) {
    (void)in_sizes; (void)n_in; (void)out_size; (void)ws_size;

    const float2* pos  = (const float2*)d_in[0];
    const float* rad   = (const float*)d_in[1];
    const float* depth = (const float*)d_in[2];

    float* out        = (float*)d_out;
    float* out_count  = out;                 // [NTILES]
    float* out_idx    = out + NTILES;        // [EE]
    float* out_depth  = out + NTILES + EE;   // [EE]

    u32* ws      = (u32*)d_ws;
    u32* counts  = ws;                   // NTILES
    u32* offsets = ws + NTILES;          // NTILES + 1
    u32* cursors = ws + 2 * NTILES + 1;  // NTILES

    // stage (pid, depth-key) directly in the output regions, overwritten by sort_kernel
    u32* stage_pid = (u32*)out_idx;
    u32* stage_key = (u32*)out_depth;

    zero_counts_kernel<<<(NTILES + 255) / 256, 256, 0, stream>>>(counts);
    hist_kernel<<<(NPTS + 255) / 256, 256, 0, stream>>>(pos, rad, counts);
    scan_kernel<<<1, 1024, 0, stream>>>(counts, offsets, cursors, out_count);
    scatter_kernel<<<(NPTS + 255) / 256, 256, 0, stream>>>(pos, rad, depth, cursors,
                                                           stage_pid, stage_key);
    fill_tail_kernel<<<(EE / 4 + 255) / 256, 256, 0, stream>>>(offsets + NTILES,
                                                               out_idx, out_depth);
    sort_kernel<<<NTILES, 256, 0, stream>>>(offsets, stage_pid, stage_key,
                                            out_idx, out_depth);
}

// Round 2
// 442.960 us; speedup vs baseline: 1.3265x; 1.3265x over previous
//
#include <hip/hip_runtime.h>
#include <stdint.h>

typedef unsigned int u32;
typedef unsigned long long u64;

#define NBW 120
#define NBH 68
#define NTILES (NBW * NBH)       // 8160
#define NPTS 500000
#define EE 12500000              // N * K * K
#define SORT_CAP 2048

__device__ __forceinline__ int clampi(int v, int lo, int hi) {
    return v < lo ? lo : (v > hi ? hi : v);
}

__device__ __forceinline__ void tile_window(float x, float y, float r,
                                            int& x0, int& x1, int& y0, int& y1) {
    // matches jnp: clip(floor_divide(x -/+ r, 16), 0, NB?) ; *0.0625f is exact
    x0 = clampi((int)floorf((x - r) * 0.0625f), 0, NBW);
    x1 = clampi((int)floorf((x + r) * 0.0625f) + 1, 0, NBW);
    y0 = clampi((int)floorf((y - r) * 0.0625f), 0, NBH);
    y1 = clampi((int)floorf((y + r) * 0.0625f) + 1, 0, NBH);
}

// monotone float -> u32 such that ascending u32 == DESCENDING float
__device__ __forceinline__ u32 depth_key(float d) {
    u32 fu = __float_as_uint(d);
    u32 asc = (fu & 0x80000000u) ? ~fu : (fu | 0x80000000u);
    return ~asc;
}
__device__ __forceinline__ float depth_unkey(u32 dk) {
    u32 asc = ~dk;
    u32 fu = (asc & 0x80000000u) ? (asc & 0x7FFFFFFFu) : ~asc;
    return __uint_as_float(fu);
}

__global__ void zero_counts_kernel(u32* __restrict__ pc, u32* __restrict__ ec) {
    int i = blockIdx.x * blockDim.x + threadIdx.x;
    if (i < NTILES) { pc[i] = 0; ec[i] = 0; }
}

// Fused histogram: per-point center-tile count, per-tile entry count, packed window.
__global__ void hist_kernel(const float2* __restrict__ pos, const float* __restrict__ rad,
                            u32* __restrict__ pc, u32* __restrict__ ec,
                            u64* __restrict__ pwin) {
    int i = blockIdx.x * blockDim.x + threadIdx.x;
    if (i >= NPTS) return;
    float2 p = pos[i];
    float r = rad[i];
    int x0, x1, y0, y1;
    tile_window(p.x, p.y, r, x0, x1, y0, y1);
    int cx = (int)(p.x * 0.0625f);   // x in [0,1920) -> cx in [0,119]
    int cy = (int)(p.y * 0.0625f);
    int ct = cx * NBH + cy;
    atomicAdd(&pc[ct], 1u);
    for (int tx = x0; tx < x1; ++tx)
        for (int ty = y0; ty < y1; ++ty)
            atomicAdd(&ec[tx * NBH + ty], 1u);
    u32 w = (u32)x0 | ((u32)y0 << 7) | ((u32)x1 << 14) | ((u32)y1 << 21);
    pwin[i] = (u64)w | ((u64)(u32)ct << 32);
}

__global__ __launch_bounds__(1024) void scan_kernel(const u32* __restrict__ pc,
                                                    u32* __restrict__ po, u32* __restrict__ pcur,
                                                    const u32* __restrict__ ec,
                                                    u32* __restrict__ eo,
                                                    float* __restrict__ out_count) {
    __shared__ u32 sA[1024], sB[1024];
    int t = threadIdx.x;
    int base = t * 8;

    // ---- scan 1: point counts -> po, pcur ----
    {
        u32 local[8]; u32 sum = 0;
#pragma unroll
        for (int j = 0; j < 8; ++j) {
            u32 c = (base + j < NTILES) ? pc[base + j] : 0u;
            local[j] = c; sum += c;
        }
        sA[t] = sum;
        __syncthreads();
        u32 *cur = sA, *nxt = sB;
        for (int off = 1; off < 1024; off <<= 1) {
            u32 v = cur[t];
            if (t >= off) v += cur[t - off];
            nxt[t] = v;
            __syncthreads();
            u32* tmp = cur; cur = nxt; nxt = tmp;
        }
        u32 run = cur[t] - sum;
#pragma unroll
        for (int j = 0; j < 8; ++j) {
            int idx = base + j;
            if (idx < NTILES) {
                po[idx] = run; pcur[idx] = run;
                run += local[j];
            }
        }
        if (t == 1023) po[NTILES] = cur[1023];
        __syncthreads();
    }

    // ---- scan 2: entry counts -> eo, out_count ----
    {
        u32 local[8]; u32 sum = 0;
#pragma unroll
        for (int j = 0; j < 8; ++j) {
            u32 c = (base + j < NTILES) ? ec[base + j] : 0u;
            local[j] = c; sum += c;
        }
        sA[t] = sum;
        __syncthreads();
        u32 *cur = sA, *nxt = sB;
        for (int off = 1; off < 1024; off <<= 1) {
            u32 v = cur[t];
            if (t >= off) v += cur[t - off];
            nxt[t] = v;
            __syncthreads();
            u32* tmp = cur; cur = nxt; nxt = tmp;
        }
        u32 run = cur[t] - sum;
#pragma unroll
        for (int j = 0; j < 8; ++j) {
            int idx = base + j;
            if (idx < NTILES) {
                eo[idx] = run;
                out_count[idx] = (float)run;
                run += local[j];
            }
        }
        if (t == 1023) eo[NTILES] = cur[1023];
    }
}

// Bin points by center tile; store packed (window | pid<<32) in sorted order.
__global__ void point_scatter_kernel(const u64* __restrict__ pwin,
                                     u32* __restrict__ pcur,
                                     u64* __restrict__ pe) {
    int i = blockIdx.x * blockDim.x + threadIdx.x;
    if (i >= NPTS) return;
    u64 w = pwin[i];
    u32 ct = (u32)(w >> 32);
    u32 slot = atomicAdd(&pcur[ct], 1u);
    pe[slot] = (w & 0xFFFFFFFFull) | ((u64)(u32)i << 32);
}

__global__ void fill_tail_kernel(const u32* __restrict__ total_ptr,
                                 float* __restrict__ out_idx, float* __restrict__ out_depth) {
    int t = blockIdx.x * blockDim.x + threadIdx.x;
    int i0 = t * 4;
    if (i0 >= EE) return;
    int total = (int)(*total_ptr);
    if (i0 >= total) {
        ((float4*)out_idx)[t]   = make_float4(-1.f, -1.f, -1.f, -1.f);
        ((float4*)out_depth)[t] = make_float4(0.f, 0.f, 0.f, 0.f);
    } else if (i0 + 4 > total) {
#pragma unroll
        for (int j = 0; j < 4; ++j) {
            int i = i0 + j;
            if (i >= total) { out_idx[i] = -1.f; out_depth[i] = 0.f; }
        }
    }
}

// One block per tile: gather candidate points from <=25 neighboring center-tile
// ranges, test window membership, LDS-append keys, bitonic sort, write output.
__global__ __launch_bounds__(256) void tile_build_kernel(const u32* __restrict__ po,
                                                         const u64* __restrict__ pe,
                                                         const float* __restrict__ depth,
                                                         const u32* __restrict__ eo,
                                                         float* __restrict__ out_idx,
                                                         float* __restrict__ out_depth) {
    __shared__ u64 keys[SORT_CAP];
    __shared__ u32 lcnt;

    int t = blockIdx.x;
    u32 base = eo[t];
    int cnt = (int)(eo[t + 1] - base);
    if (cnt <= 0) return;

    int tx = t / NBH;
    int ty = t % NBH;
    bool big = cnt > SORT_CAP;

    if (threadIdx.x == 0) lcnt = 0;
    __syncthreads();

    int cx0 = tx - 2 < 0 ? 0 : tx - 2;
    int cx1 = tx + 2 > NBW - 1 ? NBW - 1 : tx + 2;
    int cy0 = ty - 2 < 0 ? 0 : ty - 2;
    int cy1 = ty + 2 > NBH - 1 ? NBH - 1 : ty + 2;

    for (int cx = cx0; cx <= cx1; ++cx) {
        u32 s = po[cx * NBH + cy0];
        u32 e = po[cx * NBH + cy1 + 1];
        for (u32 i = s + threadIdx.x; i < e; i += 256) {
            u64 en = pe[i];
            u32 w = (u32)en;
            int x0 = (int)(w & 127u), y0 = (int)((w >> 7) & 127u);
            int x1 = (int)((w >> 14) & 127u), y1 = (int)((w >> 21) & 127u);
            if (tx >= x0 && tx < x1 && ty >= y0 && ty < y1) {
                u32 pid = (u32)(en >> 32);
                u32 dk = depth_key(depth[pid]);
                u32 slot = atomicAdd(&lcnt, 1u);
                if (!big) {
                    keys[slot] = ((u64)dk << 19) | (u64)pid;
                } else {
                    out_idx[base + slot] = (float)pid;
                    out_depth[base + slot] = depth_unkey(dk);
                }
            }
        }
    }
    __syncthreads();

    if (!big) {
        int n = 1;
        while (n < cnt) n <<= 1;
        for (int i = cnt + (int)threadIdx.x; i < n; i += 256) keys[i] = ~0ull;
        __syncthreads();
        for (int kk = 2; kk <= n; kk <<= 1) {
            for (int j = kk >> 1; j > 0; j >>= 1) {
                for (int i = threadIdx.x; i < n; i += 256) {
                    int ixj = i ^ j;
                    if (ixj > i) {
                        bool up = ((i & kk) == 0);
                        u64 a = keys[i], b = keys[ixj];
                        if ((a > b) == up) { keys[i] = b; keys[ixj] = a; }
                    }
                }
                __syncthreads();
            }
        }
        for (int i = threadIdx.x; i < cnt; i += 256) {
            u64 k = keys[i];
            u32 pid = (u32)(k & 0x7FFFFu);
            u32 dk  = (u32)(k >> 19);
            out_idx[base + i]   = (float)pid;
            out_depth[base + i] = depth_unkey(dk);
        }
    } else {
        // Statistically unreachable fallback: global odd-even transposition sort.
        for (int round = 0; round < cnt; ++round) {
            for (int i = (round & 1) + 2 * (int)threadIdx.x; i + 1 < cnt; i += 512) {
                float fi0 = out_idx[base + i], fi1 = out_idx[base + i + 1];
                float fd0 = out_depth[base + i], fd1 = out_depth[base + i + 1];
                u64 k0 = ((u64)depth_key(fd0) << 19) | (u64)(u32)fi0;
                u64 k1 = ((u64)depth_key(fd1) << 19) | (u64)(u32)fi1;
                if (k0 > k1) {
                    out_idx[base + i] = fi1; out_idx[base + i + 1] = fi0;
                    out_depth[base + i] = fd1; out_depth[base + i + 1] = fd0;
                }
            }
            __syncthreads();
        }
    }
}

extern "C" void kernel_launch(void* const* d_in, const int* in_sizes, int n_in,
                              void* d_out, int out_size, void* d_ws, size_t ws_size,
                              hipStream_t stream) {
    (void)in_sizes; (void)n_in; (void)out_size; (void)ws_size;

    const float2* pos  = (const float2*)d_in[0];
    const float* rad   = (const float*)d_in[1];
    const float* depth = (const float*)d_in[2];

    float* out        = (float*)d_out;
    float* out_count  = out;                 // [NTILES]
    float* out_idx    = out + NTILES;        // [EE]
    float* out_depth  = out + NTILES + EE;   // [EE]

    u32* ws   = (u32*)d_ws;
    u32* pc   = ws;                          // [NTILES]   point counts per center tile
    u32* po   = pc + NTILES;                 // [NTILES+1] point offsets
    u32* pcur = po + NTILES + 1;             // [NTILES]   point cursors
    u32* ec   = pcur + NTILES;               // [NTILES]   entry counts
    u32* eo   = ec + NTILES;                 // [NTILES+1] entry offsets
    u64* pwin = (u64*)(eo + NTILES + 2);     // [NPTS]  packed (window | ct<<32), 8B-aligned
    u64* pe   = pwin + NPTS;                 // [NPTS]  packed (window | pid<<32), center-sorted

    zero_counts_kernel<<<(NTILES + 255) / 256, 256, 0, stream>>>(pc, ec);
    hist_kernel<<<(NPTS + 255) / 256, 256, 0, stream>>>(pos, rad, pc, ec, pwin);
    scan_kernel<<<1, 1024, 0, stream>>>(pc, po, pcur, ec, eo, out_count);
    point_scatter_kernel<<<(NPTS + 255) / 256, 256, 0, stream>>>(pwin, pcur, pe);
    fill_tail_kernel<<<(EE / 4 + 255) / 256, 256, 0, stream>>>(eo + NTILES,
                                                               out_idx, out_depth);
    tile_build_kernel<<<NTILES, 256, 0, stream>>>(po, pe, depth, eo, out_idx, out_depth);
}

// Round 3
// 334.992 us; speedup vs baseline: 1.7540x; 1.3223x over previous
//
#include <hip/hip_runtime.h>
#include <stdint.h>

typedef unsigned int u32;
typedef unsigned long long u64;

#define NBW 120
#define NBH 68
#define NTILES (NBW * NBH)       // 8160
#define NPTS 500000
#define EE 12500000              // N * K * K
#define SORT_CAP 2048

__device__ __forceinline__ int clampi(int v, int lo, int hi) {
    return v < lo ? lo : (v > hi ? hi : v);
}

__device__ __forceinline__ void tile_window(float x, float y, float r,
                                            int& x0, int& x1, int& y0, int& y1) {
    // matches jnp: clip(floor_divide(x -/+ r, 16), 0, NB?) ; *0.0625f is exact
    x0 = clampi((int)floorf((x - r) * 0.0625f), 0, NBW);
    x1 = clampi((int)floorf((x + r) * 0.0625f) + 1, 0, NBW);
    y0 = clampi((int)floorf((y - r) * 0.0625f), 0, NBH);
    y1 = clampi((int)floorf((y + r) * 0.0625f) + 1, 0, NBH);
}

// monotone float -> u32 such that ascending u32 == DESCENDING float
__device__ __forceinline__ u32 depth_key(float d) {
    u32 fu = __float_as_uint(d);
    u32 asc = (fu & 0x80000000u) ? ~fu : (fu | 0x80000000u);
    return ~asc;
}
__device__ __forceinline__ float depth_unkey(u32 dk) {
    u32 asc = ~dk;
    u32 fu = (asc & 0x80000000u) ? (asc & 0x7FFFFFFFu) : ~asc;
    return __uint_as_float(fu);
}

// XCD-contiguous tile swizzle: each XCD gets a contiguous range of 1020 tiles,
// so its L2 only needs ~1/8 of pe/po for the candidate scans.
__device__ __forceinline__ int tile_of_block(int b) {
    return (b & 7) * (NTILES / 8) + (b >> 3);
}

__global__ void zero_counts_kernel(u32* __restrict__ pc) {
    int i = blockIdx.x * blockDim.x + threadIdx.x;
    if (i < NTILES) pc[i] = 0;
}

// Per-point: center-tile count atomic (0.5M total) + packed window record.
__global__ void hist_kernel(const float2* __restrict__ pos, const float* __restrict__ rad,
                            u32* __restrict__ pc, u64* __restrict__ pwin) {
    int i = blockIdx.x * blockDim.x + threadIdx.x;
    if (i >= NPTS) return;
    float2 p = pos[i];
    float r = rad[i];
    int x0, x1, y0, y1;
    tile_window(p.x, p.y, r, x0, x1, y0, y1);
    int cx = (int)(p.x * 0.0625f);   // x in [0,1920) -> cx in [0,119]
    int cy = (int)(p.y * 0.0625f);
    int ct = cx * NBH + cy;
    atomicAdd(&pc[ct], 1u);
    u32 w = (u32)x0 | ((u32)y0 << 7) | ((u32)x1 << 14) | ((u32)y1 << 21);
    pwin[i] = (u64)w | ((u64)(u32)ct << 32);
}

__global__ __launch_bounds__(1024) void scan_pc_kernel(const u32* __restrict__ pc,
                                                       u32* __restrict__ po,
                                                       u32* __restrict__ pcur) {
    __shared__ u32 sA[1024], sB[1024];
    int t = threadIdx.x;
    int base = t * 8;
    u32 local[8]; u32 sum = 0;
#pragma unroll
    for (int j = 0; j < 8; ++j) {
        u32 c = (base + j < NTILES) ? pc[base + j] : 0u;
        local[j] = c; sum += c;
    }
    sA[t] = sum;
    __syncthreads();
    u32 *cur = sA, *nxt = sB;
    for (int off = 1; off < 1024; off <<= 1) {
        u32 v = cur[t];
        if (t >= off) v += cur[t - off];
        nxt[t] = v;
        __syncthreads();
        u32* tmp = cur; cur = nxt; nxt = tmp;
    }
    u32 run = cur[t] - sum;
#pragma unroll
    for (int j = 0; j < 8; ++j) {
        int idx = base + j;
        if (idx < NTILES) {
            po[idx] = run; pcur[idx] = run;
            run += local[j];
        }
    }
    if (t == 1023) po[NTILES] = cur[1023];
}

__global__ __launch_bounds__(1024) void scan_ec_kernel(const u32* __restrict__ ec,
                                                       u32* __restrict__ eo,
                                                       float* __restrict__ out_count) {
    __shared__ u32 sA[1024], sB[1024];
    int t = threadIdx.x;
    int base = t * 8;
    u32 local[8]; u32 sum = 0;
#pragma unroll
    for (int j = 0; j < 8; ++j) {
        u32 c = (base + j < NTILES) ? ec[base + j] : 0u;
        local[j] = c; sum += c;
    }
    sA[t] = sum;
    __syncthreads();
    u32 *cur = sA, *nxt = sB;
    for (int off = 1; off < 1024; off <<= 1) {
        u32 v = cur[t];
        if (t >= off) v += cur[t - off];
        nxt[t] = v;
        __syncthreads();
        u32* tmp = cur; cur = nxt; nxt = tmp;
    }
    u32 run = cur[t] - sum;
#pragma unroll
    for (int j = 0; j < 8; ++j) {
        int idx = base + j;
        if (idx < NTILES) {
            eo[idx] = run;
            out_count[idx] = (float)run;
            run += local[j];
        }
    }
    if (t == 1023) eo[NTILES] = cur[1023];
}

// Bin points by center tile; store packed (window | pid<<32) in center-sorted order.
__global__ void point_scatter_kernel(const u64* __restrict__ pwin,
                                     u32* __restrict__ pcur,
                                     u64* __restrict__ pe) {
    int i = blockIdx.x * blockDim.x + threadIdx.x;
    if (i >= NPTS) return;
    u64 w = pwin[i];
    u32 ct = (u32)(w >> 32);
    u32 slot = atomicAdd(&pcur[ct], 1u);
    pe[slot] = (w & 0xFFFFFFFFull) | ((u64)(u32)i << 32);
}

// Per-tile entry count via candidate scan — zero atomics.
__global__ __launch_bounds__(256) void tile_count_kernel(const u32* __restrict__ po,
                                                         const u64* __restrict__ pe,
                                                         u32* __restrict__ ec) {
    __shared__ u32 red[256];
    int t = tile_of_block(blockIdx.x);
    int tx = t / NBH;
    int ty = t % NBH;

    int cx0 = tx - 2 < 0 ? 0 : tx - 2;
    int cx1 = tx + 2 > NBW - 1 ? NBW - 1 : tx + 2;
    int cy0 = ty - 2 < 0 ? 0 : ty - 2;
    int cy1 = ty + 2 > NBH - 1 ? NBH - 1 : ty + 2;

    u32 c = 0;
    for (int cx = cx0; cx <= cx1; ++cx) {
        u32 s = po[cx * NBH + cy0];
        u32 e = po[cx * NBH + cy1 + 1];
        for (u32 i = s + threadIdx.x; i < e; i += 256) {
            u32 w = (u32)pe[i];
            int x0 = (int)(w & 127u), y0 = (int)((w >> 7) & 127u);
            int x1 = (int)((w >> 14) & 127u), y1 = (int)((w >> 21) & 127u);
            c += (tx >= x0 && tx < x1 && ty >= y0 && ty < y1) ? 1u : 0u;
        }
    }
    red[threadIdx.x] = c;
    __syncthreads();
    for (int s = 128; s > 0; s >>= 1) {
        if ((int)threadIdx.x < s) red[threadIdx.x] += red[threadIdx.x + s];
        __syncthreads();
    }
    if (threadIdx.x == 0) ec[t] = red[0];
}

__global__ void fill_tail_kernel(const u32* __restrict__ total_ptr,
                                 float* __restrict__ out_idx, float* __restrict__ out_depth) {
    int t = blockIdx.x * blockDim.x + threadIdx.x;
    int i0 = t * 4;
    if (i0 >= EE) return;
    int total = (int)(*total_ptr);
    if (i0 >= total) {
        ((float4*)out_idx)[t]   = make_float4(-1.f, -1.f, -1.f, -1.f);
        ((float4*)out_depth)[t] = make_float4(0.f, 0.f, 0.f, 0.f);
    } else if (i0 + 4 > total) {
#pragma unroll
        for (int j = 0; j < 4; ++j) {
            int i = i0 + j;
            if (i >= total) { out_idx[i] = -1.f; out_depth[i] = 0.f; }
        }
    }
}

// One block per tile: gather candidates, LDS-append keys, wave-synchronous
// bitonic sort (j<=32 passes are wave-internal on wave64 -> no barrier), write.
__global__ __launch_bounds__(256) void tile_build_kernel(const u32* __restrict__ po,
                                                         const u64* __restrict__ pe,
                                                         const float* __restrict__ depth,
                                                         const u32* __restrict__ eo,
                                                         float* __restrict__ out_idx,
                                                         float* __restrict__ out_depth) {
    __shared__ u64 keys[SORT_CAP];
    __shared__ u32 lcnt;

    int t = tile_of_block(blockIdx.x);
    u32 base = eo[t];
    int cnt = (int)(eo[t + 1] - base);
    if (cnt <= 0) return;

    int tx = t / NBH;
    int ty = t % NBH;
    bool big = cnt > SORT_CAP;

    if (threadIdx.x == 0) lcnt = 0;
    __syncthreads();

    int cx0 = tx - 2 < 0 ? 0 : tx - 2;
    int cx1 = tx + 2 > NBW - 1 ? NBW - 1 : tx + 2;
    int cy0 = ty - 2 < 0 ? 0 : ty - 2;
    int cy1 = ty + 2 > NBH - 1 ? NBH - 1 : ty + 2;

    for (int cx = cx0; cx <= cx1; ++cx) {
        u32 s = po[cx * NBH + cy0];
        u32 e = po[cx * NBH + cy1 + 1];
        for (u32 i = s + threadIdx.x; i < e; i += 256) {
            u64 en = pe[i];
            u32 w = (u32)en;
            int x0 = (int)(w & 127u), y0 = (int)((w >> 7) & 127u);
            int x1 = (int)((w >> 14) & 127u), y1 = (int)((w >> 21) & 127u);
            if (tx >= x0 && tx < x1 && ty >= y0 && ty < y1) {
                u32 pid = (u32)(en >> 32);
                u32 dk = depth_key(depth[pid]);
                u32 slot = atomicAdd(&lcnt, 1u);
                if (!big) {
                    keys[slot] = ((u64)dk << 19) | (u64)pid;
                } else {
                    out_idx[base + slot] = (float)pid;
                    out_depth[base + slot] = depth_unkey(dk);
                }
            }
        }
    }
    __syncthreads();

    if (!big) {
        int n = 1;
        while (n < cnt) n <<= 1;
        for (int i = cnt + (int)threadIdx.x; i < n; i += 256) keys[i] = ~0ull;
        __syncthreads();
        // Wave-synchronous bitonic: element e is owned by wave (e mod 256)/64.
        // For j<=32 the partner e^j stays inside the owner wave's 64-aligned
        // chunk, so no block barrier is needed; barrier only around j>=64.
        int prevj = 0;
        for (int kk = 2; kk <= n; kk <<= 1) {
            for (int j = kk >> 1; j > 0; j >>= 1) {
                if (j >= 64 || prevj >= 64) __syncthreads();
                for (int i = threadIdx.x; i < n; i += 256) {
                    int ixj = i ^ j;
                    if (ixj > i) {
                        bool up = ((i & kk) == 0);
                        u64 a = keys[i], b = keys[ixj];
                        if ((a > b) == up) { keys[i] = b; keys[ixj] = a; }
                    }
                }
                prevj = j;
            }
        }
        __syncthreads();
        for (int i = threadIdx.x; i < cnt; i += 256) {
            u64 k = keys[i];
            u32 pid = (u32)(k & 0x7FFFFu);
            u32 dk  = (u32)(k >> 19);
            out_idx[base + i]   = (float)pid;
            out_depth[base + i] = depth_unkey(dk);
        }
    } else {
        // Statistically unreachable fallback: global odd-even transposition sort.
        for (int round = 0; round < cnt; ++round) {
            for (int i = (round & 1) + 2 * (int)threadIdx.x; i + 1 < cnt; i += 512) {
                float fi0 = out_idx[base + i], fi1 = out_idx[base + i + 1];
                float fd0 = out_depth[base + i], fd1 = out_depth[base + i + 1];
                u64 k0 = ((u64)depth_key(fd0) << 19) | (u64)(u32)fi0;
                u64 k1 = ((u64)depth_key(fd1) << 19) | (u64)(u32)fi1;
                if (k0 > k1) {
                    out_idx[base + i] = fi1; out_idx[base + i + 1] = fi0;
                    out_depth[base + i] = fd1; out_depth[base + i + 1] = fd0;
                }
            }
            __syncthreads();
        }
    }
}

extern "C" void kernel_launch(void* const* d_in, const int* in_sizes, int n_in,
                              void* d_out, int out_size, void* d_ws, size_t ws_size,
                              hipStream_t stream) {
    (void)in_sizes; (void)n_in; (void)out_size; (void)ws_size;

    const float2* pos  = (const float2*)d_in[0];
    const float* rad   = (const float*)d_in[1];
    const float* depth = (const float*)d_in[2];

    float* out        = (float*)d_out;
    float* out_count  = out;                 // [NTILES]
    float* out_idx    = out + NTILES;        // [EE]
    float* out_depth  = out + NTILES + EE;   // [EE]

    u32* ws   = (u32*)d_ws;
    u32* pc   = ws;                          // [NTILES]   point counts per center tile
    u32* po   = pc + NTILES;                 // [NTILES+1] point offsets
    u32* pcur = po + NTILES + 1;             // [NTILES]   point cursors
    u32* ec   = pcur + NTILES;               // [NTILES]   entry counts
    u32* eo   = ec + NTILES;                 // [NTILES+1] entry offsets
    u64* pwin = (u64*)(eo + NTILES + 2);     // [NPTS]  packed (window | ct<<32), 8B-aligned
    u64* pe   = pwin + NPTS;                 // [NPTS]  packed (window | pid<<32), center-sorted

    zero_counts_kernel<<<(NTILES + 255) / 256, 256, 0, stream>>>(pc);
    hist_kernel<<<(NPTS + 255) / 256, 256, 0, stream>>>(pos, rad, pc, pwin);
    scan_pc_kernel<<<1, 1024, 0, stream>>>(pc, po, pcur);
    point_scatter_kernel<<<(NPTS + 255) / 256, 256, 0, stream>>>(pwin, pcur, pe);
    tile_count_kernel<<<NTILES, 256, 0, stream>>>(po, pe, ec);
    scan_ec_kernel<<<1, 1024, 0, stream>>>(ec, eo, out_count);
    fill_tail_kernel<<<(EE / 4 + 255) / 256, 256, 0, stream>>>(eo + NTILES,
                                                               out_idx, out_depth);
    tile_build_kernel<<<NTILES, 256, 0, stream>>>(po, pe, depth, eo, out_idx, out_depth);
}

// Round 4
// 309.861 us; speedup vs baseline: 1.8963x; 1.0811x over previous
//
#include <hip/hip_runtime.h>
#include <stdint.h>

typedef unsigned int u32;
typedef unsigned long long u64;

#define NBW 120
#define NBH 68
#define NTILES (NBW * NBH)       // 8160
#define NPTS 500000
#define EE 12500000              // N * K * K
#define SORT_CAP 2048
#define HB 128                   // hist blocks
#define DX 121                   // diff array x dim (0..120)
#define DY 69                    // diff array y dim (0..68)
#define DCELLS 8352              // 121*69 = 8349, padded
#define PCW 4080                 // 8160 cells / 2 per word
#define DSLICE (HB * DCELLS)
#define PCSLICE (HB * PCW)

__device__ __forceinline__ int clampi(int v, int lo, int hi) {
    return v < lo ? lo : (v > hi ? hi : v);
}

__device__ __forceinline__ void tile_window(float x, float y, float r,
                                            int& x0, int& x1, int& y0, int& y1) {
    x0 = clampi((int)floorf((x - r) * 0.0625f), 0, NBW);
    x1 = clampi((int)floorf((x + r) * 0.0625f) + 1, 0, NBW);
    y0 = clampi((int)floorf((y - r) * 0.0625f), 0, NBH);
    y1 = clampi((int)floorf((y + r) * 0.0625f) + 1, 0, NBH);
}

// monotone float -> u32 such that ascending u32 == DESCENDING float
__device__ __forceinline__ u32 depth_key(float d) {
    u32 fu = __float_as_uint(d);
    u32 asc = (fu & 0x80000000u) ? ~fu : (fu | 0x80000000u);
    return ~asc;
}
__device__ __forceinline__ float depth_unkey(u32 dk) {
    u32 asc = ~dk;
    u32 fu = (asc & 0x80000000u) ? (asc & 0x7FFFFFFFu) : ~asc;
    return __uint_as_float(fu);
}

__device__ __forceinline__ int tile_of_block(int b) {
    return (b & 7) * (NTILES / 8) + (b >> 3);
}

__device__ __forceinline__ u64 shfl_xor_u64(u64 x, int mask) {
    int lo = __shfl_xor((int)(u32)x, mask, 64);
    int hi = __shfl_xor((int)(u32)(x >> 32), mask, 64);
    return ((u64)(u32)hi << 32) | (u64)(u32)lo;
}

__device__ __forceinline__ void lds_inc16(u32* arr, int cell) {
    atomicAdd(&arr[cell >> 1], (cell & 1) ? 0x10000u : 1u);
}

// 128 blocks: per-point window + pwin; LDS point-count histogram (packed u16)
// and LDS 2D difference-array corners (packed u16, plus/minus split). Flush
// per-block slices to the dead tail of out_depth — zero global atomics.
__global__ __launch_bounds__(1024) void hist_kernel(const float2* __restrict__ pos,
                                                    const float* __restrict__ rad,
                                                    u64* __restrict__ pwin,
                                                    u32* __restrict__ pcslc,
                                                    int* __restrict__ diffslc) {
    __shared__ u32 s_pc[PCW];
    __shared__ u32 s_dp[DCELLS / 2];
    __shared__ u32 s_dm[DCELLS / 2];
    int tid = threadIdx.x;
    for (int w = tid; w < PCW; w += 1024) s_pc[w] = 0;
    for (int w = tid; w < DCELLS / 2; w += 1024) { s_dp[w] = 0; s_dm[w] = 0; }
    __syncthreads();

    for (int i = blockIdx.x * 1024 + tid; i < NPTS; i += HB * 1024) {
        float2 p = pos[i];
        float r = rad[i];
        int x0, x1, y0, y1;
        tile_window(p.x, p.y, r, x0, x1, y0, y1);
        int cx = (int)(p.x * 0.0625f);
        int cy = (int)(p.y * 0.0625f);
        int ct = cx * NBH + cy;
        u32 w = (u32)x0 | ((u32)y0 << 7) | ((u32)x1 << 14) | ((u32)y1 << 21);
        pwin[i] = (u64)w | ((u64)(u32)ct << 32);
        lds_inc16(s_pc, ct);
        lds_inc16(s_dp, x0 * DY + y0);
        lds_inc16(s_dp, x1 * DY + y1);
        lds_inc16(s_dm, x0 * DY + y1);
        lds_inc16(s_dm, x1 * DY + y0);
    }
    __syncthreads();

    for (int w = tid; w < PCW; w += 1024) pcslc[blockIdx.x * PCW + w] = s_pc[w];
    for (int c = tid; c < DCELLS; c += 1024) {
        u32 pw = s_dp[c >> 1], mw = s_dm[c >> 1];
        int sh = (c & 1) * 16;
        int pv = (int)((pw >> sh) & 0xFFFFu);
        int mv = (int)((mw >> sh) & 0xFFFFu);
        diffslc[blockIdx.x * DCELLS + c] = pv - mv;
    }
}

// Reduce per-block slices: point counts -> counts[8160], diff -> sdg[8352].
__global__ void reduce_kernel(const u32* __restrict__ pcslc, const int* __restrict__ diffslc,
                              u32* __restrict__ counts, int* __restrict__ sdg) {
    int idx = blockIdx.x * 256 + threadIdx.x;
    if (idx < NTILES) {
        int sh = (idx & 1) * 16;
        int w = idx >> 1;
        u32 acc = 0;
        for (int s = 0; s < HB; ++s) acc += (pcslc[s * PCW + w] >> sh) & 0xFFFFu;
        counts[idx] = acc;
    } else if (idx < NTILES + DCELLS) {
        int c = idx - NTILES;
        int acc = 0;
        for (int s = 0; s < HB; ++s) acc += diffslc[s * DCELLS + c];
        sdg[c] = acc;
    }
}

__global__ __launch_bounds__(1024) void scan_pc_kernel(const u32* __restrict__ counts,
                                                       u32* __restrict__ po,
                                                       u32* __restrict__ pcur) {
    __shared__ u32 sA[1024], sB[1024];
    int t = threadIdx.x;
    int base = t * 8;
    u32 local[8]; u32 sum = 0;
#pragma unroll
    for (int j = 0; j < 8; ++j) {
        u32 c = (base + j < NTILES) ? counts[base + j] : 0u;
        local[j] = c; sum += c;
    }
    sA[t] = sum;
    __syncthreads();
    u32 *cur = sA, *nxt = sB;
    for (int off = 1; off < 1024; off <<= 1) {
        u32 v = cur[t];
        if (t >= off) v += cur[t - off];
        nxt[t] = v;
        __syncthreads();
        u32* tmp = cur; cur = nxt; nxt = tmp;
    }
    u32 run = cur[t] - sum;
#pragma unroll
    for (int j = 0; j < 8; ++j) {
        int idx = base + j;
        if (idx < NTILES) {
            po[idx] = run; pcur[idx] = run;
            run += local[j];
        }
    }
    if (t == 1023) po[NTILES] = cur[1023];
}

// 2D prefix of the reduced difference array -> per-tile entry counts, then
// the 8160-wide exclusive scan -> eo + out_count. All in one block.
__global__ __launch_bounds__(1024) void scan_ec_kernel(const int* __restrict__ sdg,
                                                       u32* __restrict__ eo,
                                                       float* __restrict__ out_count) {
    __shared__ int sd[DCELLS];
    __shared__ u32 sA[1024], sB[1024];
    int t = threadIdx.x;
    for (int c = t; c < DCELLS; c += 1024) sd[c] = sdg[c];
    __syncthreads();
    if (t < DX) { int run = 0; for (int y = 0; y < DY; ++y) { run += sd[t * DY + y]; sd[t * DY + y] = run; } }
    __syncthreads();
    if (t < DY) { int run = 0; for (int x = 0; x < DX; ++x) { run += sd[x * DY + t]; sd[x * DY + t] = run; } }
    __syncthreads();

    int base = t * 8;
    u32 local[8]; u32 sum = 0;
#pragma unroll
    for (int j = 0; j < 8; ++j) {
        int idx = base + j;
        u32 c = 0;
        if (idx < NTILES) {
            int x = idx / NBH, y = idx % NBH;
            c = (u32)sd[x * DY + y];
        }
        local[j] = c; sum += c;
    }
    sA[t] = sum;
    __syncthreads();
    u32 *cur = sA, *nxt = sB;
    for (int off = 1; off < 1024; off <<= 1) {
        u32 v = cur[t];
        if (t >= off) v += cur[t - off];
        nxt[t] = v;
        __syncthreads();
        u32* tmp = cur; cur = nxt; nxt = tmp;
    }
    u32 run = cur[t] - sum;
#pragma unroll
    for (int j = 0; j < 8; ++j) {
        int idx = base + j;
        if (idx < NTILES) {
            eo[idx] = run;
            out_count[idx] = (float)run;
            run += local[j];
        }
    }
    if (t == 1023) eo[NTILES] = cur[1023];
}

__global__ void point_scatter_kernel(const u64* __restrict__ pwin,
                                     u32* __restrict__ pcur,
                                     u64* __restrict__ pe) {
    int i = blockIdx.x * blockDim.x + threadIdx.x;
    if (i >= NPTS) return;
    u64 w = pwin[i];
    u32 ct = (u32)(w >> 32);
    u32 slot = atomicAdd(&pcur[ct], 1u);
    pe[slot] = (w & 0xFFFFFFFFull) | ((u64)(u32)i << 32);
}

__global__ void fill_tail_kernel(const u32* __restrict__ total_ptr,
                                 float* __restrict__ out_idx, float* __restrict__ out_depth) {
    int t = blockIdx.x * blockDim.x + threadIdx.x;
    int i0 = t * 4;
    if (i0 >= EE) return;
    int total = (int)(*total_ptr);
    if (i0 >= total) {
        ((float4*)out_idx)[t]   = make_float4(-1.f, -1.f, -1.f, -1.f);
        ((float4*)out_depth)[t] = make_float4(0.f, 0.f, 0.f, 0.f);
    } else if (i0 + 4 > total) {
#pragma unroll
        for (int j = 0; j < 4; ++j) {
            int i = i0 + j;
            if (i >= total) { out_idx[i] = -1.f; out_depth[i] = 0.f; }
        }
    }
}

// One block per tile: gather candidates, LDS-append keys, register/shuffle
// bitonic sort (j<=32 passes via __shfl_xor in registers; j>=64 via LDS),
// write output straight from registers.
__global__ __launch_bounds__(256) void tile_build_kernel(const u32* __restrict__ po,
                                                         const u64* __restrict__ pe,
                                                         const float* __restrict__ depth,
                                                         const u32* __restrict__ eo,
                                                         float* __restrict__ out_idx,
                                                         float* __restrict__ out_depth) {
    __shared__ u64 keys[SORT_CAP];
    __shared__ u32 lcnt;

    int t = tile_of_block(blockIdx.x);
    u32 base = eo[t];
    int cnt = (int)(eo[t + 1] - base);
    if (cnt <= 0) return;

    int tx = t / NBH;
    int ty = t % NBH;
    bool big = cnt > SORT_CAP;

    if (threadIdx.x == 0) lcnt = 0;
    __syncthreads();

    int cx0 = tx - 2 < 0 ? 0 : tx - 2;
    int cx1 = tx + 2 > NBW - 1 ? NBW - 1 : tx + 2;
    int cy0 = ty - 2 < 0 ? 0 : ty - 2;
    int cy1 = ty + 2 > NBH - 1 ? NBH - 1 : ty + 2;

    for (int cx = cx0; cx <= cx1; ++cx) {
        u32 s = po[cx * NBH + cy0];
        u32 e = po[cx * NBH + cy1 + 1];
        for (u32 i = s + threadIdx.x; i < e; i += 256) {
            u64 en = pe[i];
            u32 w = (u32)en;
            int x0 = (int)(w & 127u), y0 = (int)((w >> 7) & 127u);
            int x1 = (int)((w >> 14) & 127u), y1 = (int)((w >> 21) & 127u);
            if (tx >= x0 && tx < x1 && ty >= y0 && ty < y1) {
                u32 pid = (u32)(en >> 32);
                u32 dk = depth_key(depth[pid]);
                u32 slot = atomicAdd(&lcnt, 1u);
                if (!big) {
                    keys[slot] = ((u64)dk << 19) | (u64)pid;
                } else {
                    out_idx[base + slot] = (float)pid;
                    out_depth[base + slot] = depth_unkey(dk);
                }
            }
        }
    }
    __syncthreads();

    if (!big) {
        int n = 64;
        while (n < cnt) n <<= 1;
        for (int i = cnt + (int)threadIdx.x; i < n; i += 256) keys[i] = ~0ull;
        __syncthreads();

        int tid = threadIdx.x;
        int nv = 0;
        for (int i = tid; i < n; i += 256) nv++;   // <=8; wave-uniform (n pow2 >=64)

        u64 r[8];
        for (int v = 0; v < nv; ++v) r[v] = keys[tid + 256 * v];

        // register pass: exchange with lane^j inside the wave
        auto rpass = [&](int kk, int j) {
            for (int v = 0; v < nv; ++v) {
                int i = tid + 256 * v;
                u64 a = r[v];
                u64 b = shfl_xor_u64(a, j);
                bool up = ((i & kk) == 0);
                bool lower = ((i & j) == 0);
                u64 mn = a < b ? a : b;
                u64 mx = a < b ? b : a;
                r[v] = (lower == up) ? mn : mx;
            }
        };

        // stages kk=2..64 entirely in registers
        for (int kk = 2; kk <= 64; kk <<= 1)
            for (int j = kk >> 1; j > 0; j >>= 1)
                rpass(kk, j);

        // stages kk>=128: j>=64 via LDS, tail j<=32 in registers
        for (int kk = 128; kk <= n; kk <<= 1) {
            for (int v = 0; v < nv; ++v) keys[tid + 256 * v] = r[v];
            __syncthreads();
            for (int j = kk >> 1; j >= 64; j >>= 1) {
                for (int i = tid; i < n; i += 256) {
                    int ixj = i ^ j;
                    if (ixj > i) {
                        bool up = ((i & kk) == 0);
                        u64 a = keys[i], b = keys[ixj];
                        if ((a > b) == up) { keys[i] = b; keys[ixj] = a; }
                    }
                }
                __syncthreads();
            }
            for (int v = 0; v < nv; ++v) r[v] = keys[tid + 256 * v];
            for (int j = 32; j > 0; j >>= 1) rpass(kk, j);
        }

        // write output straight from registers
        for (int v = 0; v < nv; ++v) {
            int i = tid + 256 * v;
            if (i < cnt) {
                u64 k = r[v];
                u32 pid = (u32)(k & 0x7FFFFu);
                u32 dk  = (u32)(k >> 19);
                out_idx[base + i]   = (float)pid;
                out_depth[base + i] = depth_unkey(dk);
            }
        }
    } else {
        // Statistically unreachable fallback: global odd-even transposition sort.
        for (int round = 0; round < cnt; ++round) {
            for (int i = (round & 1) + 2 * (int)threadIdx.x; i + 1 < cnt; i += 512) {
                float fi0 = out_idx[base + i], fi1 = out_idx[base + i + 1];
                float fd0 = out_depth[base + i], fd1 = out_depth[base + i + 1];
                u64 k0 = ((u64)depth_key(fd0) << 19) | (u64)(u32)fi0;
                u64 k1 = ((u64)depth_key(fd1) << 19) | (u64)(u32)fi1;
                if (k0 > k1) {
                    out_idx[base + i] = fi1; out_idx[base + i + 1] = fi0;
                    out_depth[base + i] = fd1; out_depth[base + i + 1] = fd0;
                }
            }
            __syncthreads();
        }
    }
}

extern "C" void kernel_launch(void* const* d_in, const int* in_sizes, int n_in,
                              void* d_out, int out_size, void* d_ws, size_t ws_size,
                              hipStream_t stream) {
    (void)in_sizes; (void)n_in; (void)out_size; (void)ws_size;

    const float2* pos  = (const float2*)d_in[0];
    const float* rad   = (const float*)d_in[1];
    const float* depth = (const float*)d_in[2];

    float* out        = (float*)d_out;
    float* out_count  = out;                 // [NTILES]
    float* out_idx    = out + NTILES;        // [EE]
    float* out_depth  = out + NTILES + EE;   // [EE]

    // ws: pwin/pe (8B aligned first), then small u32 arrays
    u64* pwin   = (u64*)d_ws;                // [NPTS]
    u64* pe     = pwin + NPTS;               // [NPTS]
    u32* counts = (u32*)(pe + NPTS);         // [NTILES]
    u32* po     = counts + NTILES;           // [NTILES+1]
    u32* pcur   = po + NTILES + 1;           // [NTILES]
    u32* eo     = pcur + NTILES;             // [NTILES+1]
    int* sdg    = (int*)(eo + NTILES + 1);   // [DCELLS]

    // per-block histogram slices live in the dead tail of out_depth
    // (max live entries <= 8M floats; slices occupy the last ~1.59M floats)
    u32* pcslc   = (u32*)(out_depth + EE) - (PCSLICE + DSLICE);
    int* diffslc = (int*)(pcslc + PCSLICE);

    hist_kernel<<<HB, 1024, 0, stream>>>(pos, rad, pwin, pcslc, diffslc);
    reduce_kernel<<<(NTILES + DCELLS + 255) / 256, 256, 0, stream>>>(pcslc, diffslc,
                                                                     counts, sdg);
    scan_pc_kernel<<<1, 1024, 0, stream>>>(counts, po, pcur);
    scan_ec_kernel<<<1, 1024, 0, stream>>>(sdg, eo, out_count);
    point_scatter_kernel<<<(NPTS + 255) / 256, 256, 0, stream>>>(pwin, pcur, pe);
    fill_tail_kernel<<<(EE / 4 + 255) / 256, 256, 0, stream>>>(eo + NTILES,
                                                               out_idx, out_depth);
    tile_build_kernel<<<NTILES, 256, 0, stream>>>(po, pe, depth, eo, out_idx, out_depth);
}

// Round 5
// 264.601 us; speedup vs baseline: 2.2206x; 1.1711x over previous
//
#include <hip/hip_runtime.h>
#include <stdint.h>
#include <math.h>

typedef unsigned int u32;
typedef unsigned long long u64;

#define NBW 120
#define NBH 68
#define NTILES (NBW * NBH)       // 8160
#define NPTS 500000
#define EE 12500000              // N * K * K
#define SORT_CAP 2048
#define NBKT 1024                // distribution-sort buckets
#define HB 128                   // hist blocks
#define DX 121                   // diff array x dim (0..120)
#define DY 69                    // diff array y dim (0..68)
#define DCELLS 8352              // 121*69 = 8349, padded
#define PCW 4080                 // 8160 cells / 2 per word
#define DSLICE (HB * DCELLS)
#define PCSLICE (HB * PCW)

__device__ __forceinline__ int clampi(int v, int lo, int hi) {
    return v < lo ? lo : (v > hi ? hi : v);
}

__device__ __forceinline__ void tile_window(float x, float y, float r,
                                            int& x0, int& x1, int& y0, int& y1) {
    x0 = clampi((int)floorf((x - r) * 0.0625f), 0, NBW);
    x1 = clampi((int)floorf((x + r) * 0.0625f) + 1, 0, NBW);
    y0 = clampi((int)floorf((y - r) * 0.0625f), 0, NBH);
    y1 = clampi((int)floorf((y + r) * 0.0625f) + 1, 0, NBH);
}

// monotone float -> u32 such that ascending u32 == DESCENDING float
__device__ __forceinline__ u32 depth_key(float d) {
    u32 fu = __float_as_uint(d);
    u32 asc = (fu & 0x80000000u) ? ~fu : (fu | 0x80000000u);
    return ~asc;
}
__device__ __forceinline__ float depth_unkey(u32 dk) {
    u32 asc = ~dk;
    u32 fu = (asc & 0x80000000u) ? (asc & 0x7FFFFFFFu) : ~asc;
    return __uint_as_float(fu);
}

__device__ __forceinline__ int tile_of_block(int b) {
    return (b & 7) * (NTILES / 8) + (b >> 3);
}

// Exactly monotone (in dk) bucket map: table lookup on top-8 bits + integer
// linear interpolation. T is monotone non-decreasing, 0..NBKT.
__device__ __forceinline__ u32 bucket_of(u32 dk, const u32* __restrict__ Ts) {
    u32 k = dk >> 24;
    u32 t0 = Ts[k], t1 = Ts[k + 1];
    u32 b = t0 + (((t1 - t0) * ((dk >> 8) & 0xFFFFu)) >> 16);
    return b >= NBKT ? (NBKT - 1) : b;
}

__device__ __forceinline__ void lds_inc16(u32* arr, int cell) {
    atomicAdd(&arr[cell >> 1], (cell & 1) ? 0x10000u : 1u);
}

// 128 blocks: per-point window + pwin; LDS point-count histogram (packed u16)
// and LDS 2D difference-array corners (packed u16, plus/minus split).
__global__ __launch_bounds__(1024) void hist_kernel(const float2* __restrict__ pos,
                                                    const float* __restrict__ rad,
                                                    u64* __restrict__ pwin,
                                                    u32* __restrict__ pcslc,
                                                    int* __restrict__ diffslc) {
    __shared__ u32 s_pc[PCW];
    __shared__ u32 s_dp[DCELLS / 2];
    __shared__ u32 s_dm[DCELLS / 2];
    int tid = threadIdx.x;
    for (int w = tid; w < PCW; w += 1024) s_pc[w] = 0;
    for (int w = tid; w < DCELLS / 2; w += 1024) { s_dp[w] = 0; s_dm[w] = 0; }
    __syncthreads();

    for (int i = blockIdx.x * 1024 + tid; i < NPTS; i += HB * 1024) {
        float2 p = pos[i];
        float r = rad[i];
        int x0, x1, y0, y1;
        tile_window(p.x, p.y, r, x0, x1, y0, y1);
        int cx = (int)(p.x * 0.0625f);
        int cy = (int)(p.y * 0.0625f);
        int ct = cx * NBH + cy;
        u32 w = (u32)x0 | ((u32)y0 << 7) | ((u32)x1 << 14) | ((u32)y1 << 21);
        pwin[i] = (u64)w | ((u64)(u32)ct << 32);
        lds_inc16(s_pc, ct);
        lds_inc16(s_dp, x0 * DY + y0);
        lds_inc16(s_dp, x1 * DY + y1);
        lds_inc16(s_dm, x0 * DY + y1);
        lds_inc16(s_dm, x1 * DY + y0);
    }
    __syncthreads();

    for (int w = tid; w < PCW; w += 1024) pcslc[blockIdx.x * PCW + w] = s_pc[w];
    for (int c = tid; c < DCELLS; c += 1024) {
        u32 pw = s_dp[c >> 1], mw = s_dm[c >> 1];
        int sh = (c & 1) * 16;
        int pv = (int)((pw >> sh) & 0xFFFFu);
        int mv = (int)((mw >> sh) & 0xFFFFu);
        diffslc[blockIdx.x * DCELLS + c] = pv - mv;
    }
}

// Reduce per-block slices: point counts -> counts[8160], diff -> sdg[8352].
__global__ void reduce_kernel(const u32* __restrict__ pcslc, const int* __restrict__ diffslc,
                              u32* __restrict__ counts, int* __restrict__ sdg) {
    int idx = blockIdx.x * 256 + threadIdx.x;
    if (idx < NTILES) {
        int sh = (idx & 1) * 16;
        int w = idx >> 1;
        u32 acc = 0;
        for (int s = 0; s < HB; ++s) acc += (pcslc[s * PCW + w] >> sh) & 0xFFFFu;
        counts[idx] = acc;
    } else if (idx < NTILES + DCELLS) {
        int c = idx - NTILES;
        int acc = 0;
        for (int s = 0; s < HB; ++s) acc += diffslc[s * DCELLS + c];
        sdg[c] = acc;
    }
}

// One dispatch: point-count scan -> po/pcur; diff 2D prefix + scan -> eo +
// out_count; bucket table T (monotone-enforced) -> Tg.
__global__ __launch_bounds__(1024) void scan_all_kernel(const u32* __restrict__ counts,
                                                        u32* __restrict__ po,
                                                        u32* __restrict__ pcur,
                                                        const int* __restrict__ sdg,
                                                        u32* __restrict__ eo,
                                                        float* __restrict__ out_count,
                                                        u32* __restrict__ Tg) {
    __shared__ u32 sA[1024], sB[1024];
    __shared__ int sd[DCELLS];
    __shared__ u32 traw[257];
    int t = threadIdx.x;
    int base = t * 8;

    // ---- phase A: scan point counts ----
    {
        u32 local[8]; u32 sum = 0;
#pragma unroll
        for (int j = 0; j < 8; ++j) {
            u32 c = (base + j < NTILES) ? counts[base + j] : 0u;
            local[j] = c; sum += c;
        }
        sA[t] = sum;
        __syncthreads();
        u32 *cur = sA, *nxt = sB;
        for (int off = 1; off < 1024; off <<= 1) {
            u32 v = cur[t];
            if (t >= off) v += cur[t - off];
            nxt[t] = v;
            __syncthreads();
            u32* tmp = cur; cur = nxt; nxt = tmp;
        }
        u32 run = cur[t] - sum;
#pragma unroll
        for (int j = 0; j < 8; ++j) {
            int idx = base + j;
            if (idx < NTILES) {
                po[idx] = run; pcur[idx] = run;
                run += local[j];
            }
        }
        if (t == 1023) po[NTILES] = cur[1023];
        __syncthreads();
    }

    // ---- phase B: 2D prefix of diff array -> entry counts -> scan ----
    {
        for (int c = t; c < DCELLS; c += 1024) sd[c] = sdg[c];
        __syncthreads();
        if (t < DX) { int run = 0; for (int y = 0; y < DY; ++y) { run += sd[t * DY + y]; sd[t * DY + y] = run; } }
        __syncthreads();
        if (t < DY) { int run = 0; for (int x = 0; x < DX; ++x) { run += sd[x * DY + t]; sd[x * DY + t] = run; } }
        __syncthreads();

        u32 local[8]; u32 sum = 0;
#pragma unroll
        for (int j = 0; j < 8; ++j) {
            int idx = base + j;
            u32 c = 0;
            if (idx < NTILES) {
                int x = idx / NBH, y = idx % NBH;
                c = (u32)sd[x * DY + y];
            }
            local[j] = c; sum += c;
        }
        sA[t] = sum;
        __syncthreads();
        u32 *cur = sA, *nxt = sB;
        for (int off = 1; off < 1024; off <<= 1) {
            u32 v = cur[t];
            if (t >= off) v += cur[t - off];
            nxt[t] = v;
            __syncthreads();
            u32* tmp = cur; cur = nxt; nxt = tmp;
        }
        u32 run = cur[t] - sum;
#pragma unroll
        for (int j = 0; j < 8; ++j) {
            int idx = base + j;
            if (idx < NTILES) {
                eo[idx] = run;
                out_count[idx] = (float)run;
                run += local[j];
            }
        }
        if (t == 1023) eo[NTILES] = cur[1023];
        __syncthreads();
    }

    // ---- phase C: bucket table from normal CDF; monotone by running max ----
    if (t < 257) {
        u32 dkb = (u32)t << 24;
        float d = depth_unkey(dkb);
        float u;
        if (d != d) u = (t < 128) ? 0.f : 1.f;           // NaN regions at extremes
        else {
            float dc = fminf(fmaxf(d, -12.f), 12.f);
            u = 0.5f * erfcf(dc * 0.70710678f);          // = 1 - Phi(d), asc in dk
        }
        traw[t] = (u32)(u * (float)NBKT + 0.5f);
    }
    __syncthreads();
    if (t == 0) {
        u32 run = 0;
        for (int k = 0; k < 257; ++k) {
            u32 v = traw[k];
            if (v > NBKT) v = NBKT;
            if (v > run) run = v;
            Tg[k] = run;
        }
    }
}

__global__ void point_scatter_kernel(const u64* __restrict__ pwin,
                                     u32* __restrict__ pcur,
                                     u64* __restrict__ pe) {
    int i = blockIdx.x * blockDim.x + threadIdx.x;
    if (i >= NPTS) return;
    u64 w = pwin[i];
    u32 ct = (u32)(w >> 32);
    u32 slot = atomicAdd(&pcur[ct], 1u);
    pe[slot] = (w & 0xFFFFFFFFull) | ((u64)(u32)i << 32);
}

// One block per tile: tail-fill slice + two-pass candidate gather into 1024
// depth-CDF buckets + per-thread insertion sort per bucket + coalesced write.
__global__ __launch_bounds__(256) void tile_build_kernel(const u32* __restrict__ po,
                                                         const u64* __restrict__ pe,
                                                         const float* __restrict__ depth,
                                                         const u32* __restrict__ eo,
                                                         const u32* __restrict__ Tg,
                                                         float* __restrict__ out_idx,
                                                         float* __restrict__ out_depth) {
    __shared__ u64 keys[SORT_CAP];          // 16 KB
    __shared__ u32 boff[NBKT + 1];          // 4 KB + 4  (hist -> exclusive offsets)
    __shared__ u32 bcur[NBKT];              // 4 KB      (scatter cursors)
    __shared__ u32 Ts[257];
    __shared__ u32 wsum[4];
    __shared__ u32 lcnt;

    int tid = threadIdx.x;
    int lane = tid & 63;
    int wv = tid >> 6;

    // ---- fused tail fill: pad [total, EE) with -1 / 0 ----
    {
        u32 total = eo[NTILES];
        u32 tailn = EE - total;
        u32 per = (tailn + NTILES - 1) / NTILES;
        u64 s = (u64)total + (u64)blockIdx.x * per;
        u64 e = s + per; if (e > (u64)EE) e = EE;
        for (u64 i = s + tid; i < e; i += 256) {
            out_idx[i] = -1.f;
            out_depth[i] = 0.f;
        }
    }

    int t = tile_of_block(blockIdx.x);
    u32 base = eo[t];
    int cnt = (int)(eo[t + 1] - base);
    if (cnt <= 0) return;

    int tx = t / NBH;
    int ty = t % NBH;
    bool big = cnt > SORT_CAP;

    // init LDS
    for (int b = tid; b < NBKT; b += 256) boff[b] = 0;
    for (int k = tid; k < 257; k += 256) Ts[k] = Tg[k];
    if (tid == 0) lcnt = 0;
    __syncthreads();

    int cx0 = tx - 2 < 0 ? 0 : tx - 2;
    int cx1 = tx + 2 > NBW - 1 ? NBW - 1 : tx + 2;
    int cy0 = ty - 2 < 0 ? 0 : ty - 2;
    int cy1 = ty + 2 > NBH - 1 ? NBH - 1 : ty + 2;

    if (!big) {
        // ---- pass 1: bucket histogram ----
        for (int cx = cx0; cx <= cx1; ++cx) {
            u32 s = po[cx * NBH + cy0];
            u32 e = po[cx * NBH + cy1 + 1];
            for (u32 i = s + tid; i < e; i += 256) {
                u64 en = pe[i];
                u32 w = (u32)en;
                int x0 = (int)(w & 127u), y0 = (int)((w >> 7) & 127u);
                int x1 = (int)((w >> 14) & 127u), y1 = (int)((w >> 21) & 127u);
                if (tx >= x0 && tx < x1 && ty >= y0 && ty < y1) {
                    u32 pid = (u32)(en >> 32);
                    u32 dk = depth_key(depth[pid]);
                    atomicAdd(&boff[bucket_of(dk, Ts)], 1u);
                }
            }
        }
        __syncthreads();

        // ---- exclusive scan of 1024 buckets (4 per thread + shfl scan) ----
        {
            int b0 = tid * 4;
            u32 h0 = boff[b0], h1 = boff[b0 + 1], h2 = boff[b0 + 2], h3 = boff[b0 + 3];
            u32 tsum = h0 + h1 + h2 + h3;
            u32 v = tsum;
            for (int off = 1; off < 64; off <<= 1) {
                u32 n = __shfl_up(v, off, 64);
                if (lane >= off) v += n;
            }
            if (lane == 63) wsum[wv] = v;
            __syncthreads();
            u32 wpre = 0;
            for (int w = 0; w < wv; ++w) wpre += wsum[w];
            u32 run = wpre + v - tsum;
            boff[b0] = run;     bcur[b0] = run;     run += h0;
            boff[b0 + 1] = run; bcur[b0 + 1] = run; run += h1;
            boff[b0 + 2] = run; bcur[b0 + 2] = run; run += h2;
            boff[b0 + 3] = run; bcur[b0 + 3] = run; run += h3;
            if (tid == 255) boff[NBKT] = run;
        }
        __syncthreads();

        // ---- pass 2: scatter keys into bucketed order ----
        for (int cx = cx0; cx <= cx1; ++cx) {
            u32 s = po[cx * NBH + cy0];
            u32 e = po[cx * NBH + cy1 + 1];
            for (u32 i = s + tid; i < e; i += 256) {
                u64 en = pe[i];
                u32 w = (u32)en;
                int x0 = (int)(w & 127u), y0 = (int)((w >> 7) & 127u);
                int x1 = (int)((w >> 14) & 127u), y1 = (int)((w >> 21) & 127u);
                if (tx >= x0 && tx < x1 && ty >= y0 && ty < y1) {
                    u32 pid = (u32)(en >> 32);
                    u32 dk = depth_key(depth[pid]);
                    u32 slot = atomicAdd(&bcur[bucket_of(dk, Ts)], 1u);
                    keys[slot] = ((u64)dk << 19) | (u64)pid;
                }
            }
        }
        __syncthreads();

        // ---- per-thread insertion sort of each bucket ----
        for (int b = tid; b < NBKT; b += 256) {
            int s = (int)boff[b], e = (int)boff[b + 1];
            for (int i = s + 1; i < e; ++i) {
                u64 k = keys[i];
                int j = i - 1;
                while (j >= s && keys[j] > k) { keys[j + 1] = keys[j]; --j; }
                keys[j + 1] = k;
            }
        }
        __syncthreads();

        // ---- decode + coalesced write ----
        for (int i = tid; i < cnt; i += 256) {
            u64 k = keys[i];
            u32 pid = (u32)(k & 0x7FFFFu);
            u32 dk  = (u32)(k >> 19);
            out_idx[base + i]   = (float)pid;
            out_depth[base + i] = depth_unkey(dk);
        }
    } else {
        // Statistically unreachable fallback: append to global, odd-even sort.
        for (int cx = cx0; cx <= cx1; ++cx) {
            u32 s = po[cx * NBH + cy0];
            u32 e = po[cx * NBH + cy1 + 1];
            for (u32 i = s + tid; i < e; i += 256) {
                u64 en = pe[i];
                u32 w = (u32)en;
                int x0 = (int)(w & 127u), y0 = (int)((w >> 7) & 127u);
                int x1 = (int)((w >> 14) & 127u), y1 = (int)((w >> 21) & 127u);
                if (tx >= x0 && tx < x1 && ty >= y0 && ty < y1) {
                    u32 pid = (u32)(en >> 32);
                    u32 dk = depth_key(depth[pid]);
                    u32 slot = atomicAdd(&lcnt, 1u);
                    out_idx[base + slot] = (float)pid;
                    out_depth[base + slot] = depth_unkey(dk);
                }
            }
        }
        __syncthreads();
        for (int round = 0; round < cnt; ++round) {
            for (int i = (round & 1) + 2 * tid; i + 1 < cnt; i += 512) {
                float fi0 = out_idx[base + i], fi1 = out_idx[base + i + 1];
                float fd0 = out_depth[base + i], fd1 = out_depth[base + i + 1];
                u64 k0 = ((u64)depth_key(fd0) << 19) | (u64)(u32)fi0;
                u64 k1 = ((u64)depth_key(fd1) << 19) | (u64)(u32)fi1;
                if (k0 > k1) {
                    out_idx[base + i] = fi1; out_idx[base + i + 1] = fi0;
                    out_depth[base + i] = fd1; out_depth[base + i + 1] = fd0;
                }
            }
            __syncthreads();
        }
    }
}

extern "C" void kernel_launch(void* const* d_in, const int* in_sizes, int n_in,
                              void* d_out, int out_size, void* d_ws, size_t ws_size,
                              hipStream_t stream) {
    (void)in_sizes; (void)n_in; (void)out_size; (void)ws_size;

    const float2* pos  = (const float2*)d_in[0];
    const float* rad   = (const float*)d_in[1];
    const float* depth = (const float*)d_in[2];

    float* out        = (float*)d_out;
    float* out_count  = out;                 // [NTILES]
    float* out_idx    = out + NTILES;        // [EE]
    float* out_depth  = out + NTILES + EE;   // [EE]

    // ws layout: u64 arrays first (alignment), then u32 arrays
    u64* pwin   = (u64*)d_ws;                // [NPTS]
    u64* pe     = pwin + NPTS;               // [NPTS]
    u32* counts = (u32*)(pe + NPTS);         // [NTILES]
    u32* po     = counts + NTILES;           // [NTILES+1]
    u32* pcur   = po + NTILES + 1;           // [NTILES]
    u32* eo     = pcur + NTILES;             // [NTILES+1]
    int* sdg    = (int*)(eo + NTILES + 1);   // [DCELLS]
    u32* Tg     = (u32*)(sdg + DCELLS);      // [257]

    // per-block histogram slices live in the dead tail of out_depth
    // (live entries ~3.6M of 12.5M; slices occupy the last ~1.59M floats)
    u32* pcslc   = (u32*)(out_depth + EE) - (PCSLICE + DSLICE);
    int* diffslc = (int*)(pcslc + PCSLICE);

    hist_kernel<<<HB, 1024, 0, stream>>>(pos, rad, pwin, pcslc, diffslc);
    reduce_kernel<<<(NTILES + DCELLS + 255) / 256, 256, 0, stream>>>(pcslc, diffslc,
                                                                     counts, sdg);
    scan_all_kernel<<<1, 1024, 0, stream>>>(counts, po, pcur, sdg, eo, out_count, Tg);
    point_scatter_kernel<<<(NPTS + 255) / 256, 256, 0, stream>>>(pwin, pcur, pe);
    tile_build_kernel<<<NTILES, 256, 0, stream>>>(po, pe, depth, eo, Tg,
                                                  out_idx, out_depth);
}

// Round 6
// 233.164 us; speedup vs baseline: 2.5200x; 1.1348x over previous
//
#include <hip/hip_runtime.h>
#include <stdint.h>
#include <math.h>

typedef unsigned int u32;
typedef unsigned long long u64;

#define NBW 120
#define NBH 68
#define NTILES (NBW * NBH)       // 8160
#define NPTS 500000
#define EE 12500000              // N * K * K
#define SORT_CAP 2048
#define NBKT 1024                // distribution-sort buckets
#define HB 128                   // hist blocks
#define DX 121                   // diff array x dim (0..120)
#define DY 69                    // diff array y dim (0..68)
#define DCELLS 8352              // 121*69 = 8349, padded
#define PCW 4080                 // 8160 cells / 2 per word
#define DSLICE (HB * DCELLS)
#define PCSLICE (HB * PCW)

__device__ __forceinline__ int clampi(int v, int lo, int hi) {
    return v < lo ? lo : (v > hi ? hi : v);
}

__device__ __forceinline__ void tile_window(float x, float y, float r,
                                            int& x0, int& x1, int& y0, int& y1) {
    x0 = clampi((int)floorf((x - r) * 0.0625f), 0, NBW);
    x1 = clampi((int)floorf((x + r) * 0.0625f) + 1, 0, NBW);
    y0 = clampi((int)floorf((y - r) * 0.0625f), 0, NBH);
    y1 = clampi((int)floorf((y + r) * 0.0625f) + 1, 0, NBH);
}

// monotone float -> u32 such that ascending u32 == DESCENDING float
__device__ __forceinline__ u32 depth_key(float d) {
    u32 fu = __float_as_uint(d);
    u32 asc = (fu & 0x80000000u) ? ~fu : (fu | 0x80000000u);
    return ~asc;
}
__device__ __forceinline__ float depth_unkey(u32 dk) {
    u32 asc = ~dk;
    u32 fu = (asc & 0x80000000u) ? (asc & 0x7FFFFFFFu) : ~asc;
    return __uint_as_float(fu);
}

__device__ __forceinline__ int tile_of_block(int b) {
    return (b & 7) * (NTILES / 8) + (b >> 3);
}

// Exactly monotone (in dk) bucket map: table lookup on top-8 bits + integer
// linear interpolation. T is monotone non-decreasing, 0..NBKT.
__device__ __forceinline__ u32 bucket_of(u32 dk, const u32* __restrict__ Ts) {
    u32 k = dk >> 24;
    u32 t0 = Ts[k], t1 = Ts[k + 1];
    u32 b = t0 + (((t1 - t0) * ((dk >> 8) & 0xFFFFu)) >> 16);
    return b >= NBKT ? (NBKT - 1) : b;
}

__device__ __forceinline__ void lds_inc16(u32* arr, int cell) {
    atomicAdd(&arr[cell >> 1], (cell & 1) ? 0x10000u : 1u);
}

// 128 blocks: per-point window + pwin; LDS point-count histogram (packed u16)
// and LDS 2D difference-array corners (packed u16, plus/minus split).
__global__ __launch_bounds__(1024) void hist_kernel(const float2* __restrict__ pos,
                                                    const float* __restrict__ rad,
                                                    u64* __restrict__ pwin,
                                                    u32* __restrict__ pcslc,
                                                    int* __restrict__ diffslc) {
    __shared__ u32 s_pc[PCW];
    __shared__ u32 s_dp[DCELLS / 2];
    __shared__ u32 s_dm[DCELLS / 2];
    int tid = threadIdx.x;
    for (int w = tid; w < PCW; w += 1024) s_pc[w] = 0;
    for (int w = tid; w < DCELLS / 2; w += 1024) { s_dp[w] = 0; s_dm[w] = 0; }
    __syncthreads();

    for (int i = blockIdx.x * 1024 + tid; i < NPTS; i += HB * 1024) {
        float2 p = pos[i];
        float r = rad[i];
        int x0, x1, y0, y1;
        tile_window(p.x, p.y, r, x0, x1, y0, y1);
        int cx = (int)(p.x * 0.0625f);
        int cy = (int)(p.y * 0.0625f);
        int ct = cx * NBH + cy;
        u32 w = (u32)x0 | ((u32)y0 << 7) | ((u32)x1 << 14) | ((u32)y1 << 21);
        pwin[i] = (u64)w | ((u64)(u32)ct << 32);
        lds_inc16(s_pc, ct);
        lds_inc16(s_dp, x0 * DY + y0);
        lds_inc16(s_dp, x1 * DY + y1);
        lds_inc16(s_dm, x0 * DY + y1);
        lds_inc16(s_dm, x1 * DY + y0);
    }
    __syncthreads();

    for (int w = tid; w < PCW; w += 1024) pcslc[blockIdx.x * PCW + w] = s_pc[w];
    for (int c = tid; c < DCELLS; c += 1024) {
        u32 pw = s_dp[c >> 1], mw = s_dm[c >> 1];
        int sh = (c & 1) * 16;
        int pv = (int)((pw >> sh) & 0xFFFFu);
        int mv = (int)((mw >> sh) & 0xFFFFu);
        diffslc[blockIdx.x * DCELLS + c] = pv - mv;
    }
}

// Reduce per-block slices: point counts -> counts[8160], diff -> sdg[8352].
__global__ void reduce_kernel(const u32* __restrict__ pcslc, const int* __restrict__ diffslc,
                              u32* __restrict__ counts, int* __restrict__ sdg) {
    int idx = blockIdx.x * 256 + threadIdx.x;
    if (idx < NTILES) {
        int sh = (idx & 1) * 16;
        int w = idx >> 1;
        u32 acc = 0;
        for (int s = 0; s < HB; ++s) acc += (pcslc[s * PCW + w] >> sh) & 0xFFFFu;
        counts[idx] = acc;
    } else if (idx < NTILES + DCELLS) {
        int c = idx - NTILES;
        int acc = 0;
        for (int s = 0; s < HB; ++s) acc += diffslc[s * DCELLS + c];
        sdg[c] = acc;
    }
}

// One dispatch: point-count scan -> po; diff 2D prefix + scan -> eo +
// out_count; bucket table T (monotone-enforced) -> Tg.
__global__ __launch_bounds__(1024) void scan_all_kernel(const u32* __restrict__ counts,
                                                        u32* __restrict__ po,
                                                        const int* __restrict__ sdg,
                                                        u32* __restrict__ eo,
                                                        float* __restrict__ out_count,
                                                        u32* __restrict__ Tg) {
    __shared__ u32 sA[1024], sB[1024];
    __shared__ int sd[DCELLS];
    __shared__ u32 traw[257];
    int t = threadIdx.x;
    int base = t * 8;

    // ---- phase A: scan point counts ----
    {
        u32 local[8]; u32 sum = 0;
#pragma unroll
        for (int j = 0; j < 8; ++j) {
            u32 c = (base + j < NTILES) ? counts[base + j] : 0u;
            local[j] = c; sum += c;
        }
        sA[t] = sum;
        __syncthreads();
        u32 *cur = sA, *nxt = sB;
        for (int off = 1; off < 1024; off <<= 1) {
            u32 v = cur[t];
            if (t >= off) v += cur[t - off];
            nxt[t] = v;
            __syncthreads();
            u32* tmp = cur; cur = nxt; nxt = tmp;
        }
        u32 run = cur[t] - sum;
#pragma unroll
        for (int j = 0; j < 8; ++j) {
            int idx = base + j;
            if (idx < NTILES) {
                po[idx] = run;
                run += local[j];
            }
        }
        if (t == 1023) po[NTILES] = cur[1023];
        __syncthreads();
    }

    // ---- phase B: 2D prefix of diff array -> entry counts -> scan ----
    {
        for (int c = t; c < DCELLS; c += 1024) sd[c] = sdg[c];
        __syncthreads();
        if (t < DX) { int run = 0; for (int y = 0; y < DY; ++y) { run += sd[t * DY + y]; sd[t * DY + y] = run; } }
        __syncthreads();
        if (t < DY) { int run = 0; for (int x = 0; x < DX; ++x) { run += sd[x * DY + t]; sd[x * DY + t] = run; } }
        __syncthreads();

        u32 local[8]; u32 sum = 0;
#pragma unroll
        for (int j = 0; j < 8; ++j) {
            int idx = base + j;
            u32 c = 0;
            if (idx < NTILES) {
                int x = idx / NBH, y = idx % NBH;
                c = (u32)sd[x * DY + y];
            }
            local[j] = c; sum += c;
        }
        sA[t] = sum;
        __syncthreads();
        u32 *cur = sA, *nxt = sB;
        for (int off = 1; off < 1024; off <<= 1) {
            u32 v = cur[t];
            if (t >= off) v += cur[t - off];
            nxt[t] = v;
            __syncthreads();
            u32* tmp = cur; cur = nxt; nxt = tmp;
        }
        u32 run = cur[t] - sum;
#pragma unroll
        for (int j = 0; j < 8; ++j) {
            int idx = base + j;
            if (idx < NTILES) {
                eo[idx] = run;
                out_count[idx] = (float)run;
                run += local[j];
            }
        }
        if (t == 1023) eo[NTILES] = cur[1023];
        __syncthreads();
    }

    // ---- phase C: bucket table from normal CDF; monotone by running max ----
    if (t < 257) {
        u32 dkb = (u32)t << 24;
        float d = depth_unkey(dkb);
        float u;
        if (d != d) u = (t < 128) ? 0.f : 1.f;           // NaN regions at extremes
        else {
            float dc = fminf(fmaxf(d, -12.f), 12.f);
            u = 0.5f * erfcf(dc * 0.70710678f);          // = 1 - Phi(d), asc in dk
        }
        traw[t] = (u32)(u * (float)NBKT + 0.5f);
    }
    __syncthreads();
    if (t == 0) {
        u32 run = 0;
        for (int k = 0; k < 257; ++k) {
            u32 v = traw[k];
            if (v > NBKT) v = NBKT;
            if (v > run) run = v;
            Tg[k] = run;
        }
    }
}

// Per-(hist-block, tile) exclusive base offsets from the per-block slices.
__global__ void colscan_kernel(const u32* __restrict__ pcslc,
                               const u32* __restrict__ po,
                               u32* __restrict__ ctab) {
    int t = blockIdx.x * 256 + threadIdx.x;
    if (t >= NTILES) return;
    u32 run = po[t];
    int w = t >> 1, sh = (t & 1) * 16;
    for (int b = 0; b < HB; ++b) {
        ctab[b * NTILES + t] = run;
        run += (pcslc[b * PCW + w] >> sh) & 0xFFFFu;
    }
}

// Same block<->point mapping as hist; LDS cursor row from ctab -> LDS atomics
// only. Writes 16B records {key=(dk<<19)|pid, window} in center-sorted order.
__global__ __launch_bounds__(1024) void point_scatter_kernel(const u64* __restrict__ pwin,
                                                             const float* __restrict__ depth,
                                                             const u32* __restrict__ ctab,
                                                             ulonglong2* __restrict__ pe16) {
    __shared__ u32 cur[NTILES];
    int tid = threadIdx.x;
    for (int w = tid; w < NTILES; w += 1024) cur[w] = ctab[blockIdx.x * NTILES + w];
    __syncthreads();
    for (int i = blockIdx.x * 1024 + tid; i < NPTS; i += HB * 1024) {
        u64 w = pwin[i];
        u32 ct = (u32)(w >> 32);
        u32 dk = depth_key(depth[i]);
        u32 slot = atomicAdd(&cur[ct], 1u);
        pe16[slot] = make_ulonglong2(((u64)dk << 19) | (u64)(u32)i, w & 0xFFFFFFFFull);
    }
}

// One block per tile: tail-fill slice + two coalesced candidate passes over
// 16B records (no dependent gathers) into 1024 depth-CDF buckets +
// per-thread insertion sort per bucket + coalesced write.
__global__ __launch_bounds__(256) void tile_build_kernel(const u32* __restrict__ po,
                                                         const ulonglong2* __restrict__ pe16,
                                                         const u32* __restrict__ eo,
                                                         const u32* __restrict__ Tg,
                                                         float* __restrict__ out_idx,
                                                         float* __restrict__ out_depth) {
    __shared__ u64 keys[SORT_CAP];          // 16 KB
    __shared__ u32 boff[NBKT + 1];          // hist -> exclusive offsets
    __shared__ u32 bcur[NBKT];              // scatter cursors
    __shared__ u32 Ts[257];
    __shared__ u32 wsum[4];
    __shared__ u32 lcnt;

    int tid = threadIdx.x;
    int lane = tid & 63;
    int wv = tid >> 6;

    // ---- fused tail fill: pad [total, EE) with -1 / 0 ----
    {
        u32 total = eo[NTILES];
        u32 tailn = EE - total;
        u32 per = (tailn + NTILES - 1) / NTILES;
        u64 s = (u64)total + (u64)blockIdx.x * per;
        u64 e = s + per; if (e > (u64)EE) e = EE;
        for (u64 i = s + tid; i < e; i += 256) {
            out_idx[i] = -1.f;
            out_depth[i] = 0.f;
        }
    }

    int t = tile_of_block(blockIdx.x);
    u32 base = eo[t];
    int cnt = (int)(eo[t + 1] - base);
    if (cnt <= 0) return;

    int tx = t / NBH;
    int ty = t % NBH;
    bool big = cnt > SORT_CAP;

    for (int b = tid; b < NBKT; b += 256) boff[b] = 0;
    for (int k = tid; k < 257; k += 256) Ts[k] = Tg[k];
    if (tid == 0) lcnt = 0;
    __syncthreads();

    int cx0 = tx - 2 < 0 ? 0 : tx - 2;
    int cx1 = tx + 2 > NBW - 1 ? NBW - 1 : tx + 2;
    int cy0 = ty - 2 < 0 ? 0 : ty - 2;
    int cy1 = ty + 2 > NBH - 1 ? NBH - 1 : ty + 2;

    if (!big) {
        // ---- pass 1: bucket histogram (coalesced 16B loads, no gathers) ----
        for (int cx = cx0; cx <= cx1; ++cx) {
            u32 s = po[cx * NBH + cy0];
            u32 e = po[cx * NBH + cy1 + 1];
            for (u32 i = s + tid; i < e; i += 256) {
                ulonglong2 en = pe16[i];
                u32 w = (u32)en.y;
                int x0 = (int)(w & 127u), y0 = (int)((w >> 7) & 127u);
                int x1 = (int)((w >> 14) & 127u), y1 = (int)((w >> 21) & 127u);
                if (tx >= x0 && tx < x1 && ty >= y0 && ty < y1) {
                    u32 dk = (u32)(en.x >> 19);
                    atomicAdd(&boff[bucket_of(dk, Ts)], 1u);
                }
            }
        }
        __syncthreads();

        // ---- exclusive scan of 1024 buckets (4 per thread + shfl scan) ----
        {
            int b0 = tid * 4;
            u32 h0 = boff[b0], h1 = boff[b0 + 1], h2 = boff[b0 + 2], h3 = boff[b0 + 3];
            u32 tsum = h0 + h1 + h2 + h3;
            u32 v = tsum;
            for (int off = 1; off < 64; off <<= 1) {
                u32 n = __shfl_up(v, off, 64);
                if (lane >= off) v += n;
            }
            if (lane == 63) wsum[wv] = v;
            __syncthreads();
            u32 wpre = 0;
            for (int w = 0; w < wv; ++w) wpre += wsum[w];
            u32 run = wpre + v - tsum;
            boff[b0] = run;     bcur[b0] = run;     run += h0;
            boff[b0 + 1] = run; bcur[b0 + 1] = run; run += h1;
            boff[b0 + 2] = run; bcur[b0 + 2] = run; run += h2;
            boff[b0 + 3] = run; bcur[b0 + 3] = run; run += h3;
            if (tid == 255) boff[NBKT] = run;
        }
        __syncthreads();

        // ---- pass 2: scatter keys into bucketed order ----
        for (int cx = cx0; cx <= cx1; ++cx) {
            u32 s = po[cx * NBH + cy0];
            u32 e = po[cx * NBH + cy1 + 1];
            for (u32 i = s + tid; i < e; i += 256) {
                ulonglong2 en = pe16[i];
                u32 w = (u32)en.y;
                int x0 = (int)(w & 127u), y0 = (int)((w >> 7) & 127u);
                int x1 = (int)((w >> 14) & 127u), y1 = (int)((w >> 21) & 127u);
                if (tx >= x0 && tx < x1 && ty >= y0 && ty < y1) {
                    u32 dk = (u32)(en.x >> 19);
                    u32 slot = atomicAdd(&bcur[bucket_of(dk, Ts)], 1u);
                    keys[slot] = en.x;
                }
            }
        }
        __syncthreads();

        // ---- per-thread insertion sort of each bucket ----
        for (int b = tid; b < NBKT; b += 256) {
            int s = (int)boff[b], e = (int)boff[b + 1];
            for (int i = s + 1; i < e; ++i) {
                u64 k = keys[i];
                int j = i - 1;
                while (j >= s && keys[j] > k) { keys[j + 1] = keys[j]; --j; }
                keys[j + 1] = k;
            }
        }
        __syncthreads();

        // ---- decode + coalesced write ----
        for (int i = tid; i < cnt; i += 256) {
            u64 k = keys[i];
            u32 pid = (u32)(k & 0x7FFFFu);
            u32 dk  = (u32)(k >> 19);
            out_idx[base + i]   = (float)pid;
            out_depth[base + i] = depth_unkey(dk);
        }
    } else {
        // Statistically unreachable fallback: append to global, odd-even sort.
        for (int cx = cx0; cx <= cx1; ++cx) {
            u32 s = po[cx * NBH + cy0];
            u32 e = po[cx * NBH + cy1 + 1];
            for (u32 i = s + tid; i < e; i += 256) {
                ulonglong2 en = pe16[i];
                u32 w = (u32)en.y;
                int x0 = (int)(w & 127u), y0 = (int)((w >> 7) & 127u);
                int x1 = (int)((w >> 14) & 127u), y1 = (int)((w >> 21) & 127u);
                if (tx >= x0 && tx < x1 && ty >= y0 && ty < y1) {
                    u32 pid = (u32)(en.x & 0x7FFFFu);
                    u32 dk  = (u32)(en.x >> 19);
                    u32 slot = atomicAdd(&lcnt, 1u);
                    out_idx[base + slot] = (float)pid;
                    out_depth[base + slot] = depth_unkey(dk);
                }
            }
        }
        __syncthreads();
        for (int round = 0; round < cnt; ++round) {
            for (int i = (round & 1) + 2 * tid; i + 1 < cnt; i += 512) {
                float fi0 = out_idx[base + i], fi1 = out_idx[base + i + 1];
                float fd0 = out_depth[base + i], fd1 = out_depth[base + i + 1];
                u64 k0 = ((u64)depth_key(fd0) << 19) | (u64)(u32)fi0;
                u64 k1 = ((u64)depth_key(fd1) << 19) | (u64)(u32)fi1;
                if (k0 > k1) {
                    out_idx[base + i] = fi1; out_idx[base + i + 1] = fi0;
                    out_depth[base + i] = fd1; out_depth[base + i + 1] = fd0;
                }
            }
            __syncthreads();
        }
    }
}

extern "C" void kernel_launch(void* const* d_in, const int* in_sizes, int n_in,
                              void* d_out, int out_size, void* d_ws, size_t ws_size,
                              hipStream_t stream) {
    (void)in_sizes; (void)n_in; (void)out_size; (void)ws_size;

    const float2* pos  = (const float2*)d_in[0];
    const float* rad   = (const float*)d_in[1];
    const float* depth = (const float*)d_in[2];

    float* out        = (float*)d_out;
    float* out_count  = out;                 // [NTILES]
    float* out_idx    = out + NTILES;        // [EE]
    float* out_depth  = out + NTILES + EE;   // [EE]

    // ws layout: 16B records first (alignment), then u32 arrays (~8.1 MB total)
    ulonglong2* pe16 = (ulonglong2*)d_ws;    // [NPTS] {key, window}
    u32* counts = (u32*)(pe16 + NPTS);       // [NTILES]
    u32* po     = counts + NTILES;           // [NTILES+1]
    u32* eo     = po + NTILES + 1;           // [NTILES+1]
    int* sdg    = (int*)(eo + NTILES + 1);   // [DCELLS]
    u32* Tg     = (u32*)(sdg + DCELLS);      // [257]

    // Large staging lives in the guaranteed-dead output tail (total entries
    // <= 8M of 12.5M since radius < 24 -> window <= 4x4; tail >= 18 MB/array).
    // tile_build's fused tail-fill overwrites these regions last.
    u32* ctab = (u32*)out_idx + (EE - HB * NTILES);            // [HB*NTILES]
    u64* pwin = (u64*)((u32*)out_idx + (EE - HB * NTILES - 2 * NPTS));  // [NPTS]
    u32* pcslc   = (u32*)(out_depth + EE) - (PCSLICE + DSLICE);
    int* diffslc = (int*)(pcslc + PCSLICE);

    hist_kernel<<<HB, 1024, 0, stream>>>(pos, rad, pwin, pcslc, diffslc);
    reduce_kernel<<<(NTILES + DCELLS + 255) / 256, 256, 0, stream>>>(pcslc, diffslc,
                                                                     counts, sdg);
    scan_all_kernel<<<1, 1024, 0, stream>>>(counts, po, sdg, eo, out_count, Tg);
    colscan_kernel<<<(NTILES + 255) / 256, 256, 0, stream>>>(pcslc, po, ctab);
    point_scatter_kernel<<<HB, 1024, 0, stream>>>(pwin, depth, ctab, pe16);
    tile_build_kernel<<<NTILES, 256, 0, stream>>>(po, pe16, eo, Tg,
                                                  out_idx, out_depth);
}

// Round 7
// 221.462 us; speedup vs baseline: 2.6532x; 1.0528x over previous
//
#include <hip/hip_runtime.h>
#include <stdint.h>
#include <math.h>

typedef unsigned int u32;
typedef unsigned long long u64;

#define NBW 120
#define NBH 68
#define NTILES (NBW * NBH)       // 8160
#define NPTS 500000
#define EE 12500000              // N * K * K
#define SORT_CAP 2048
#define NBKT 1024                // distribution-sort buckets
#define HB 256                   // hist/scatter blocks (all CUs)
#define HT 512                   // hist/scatter threads per block
#define DX 121                   // diff array x dim (0..120)
#define DY 69                    // diff array y dim (0..68)
#define DCELLS 8352              // 121*69 = 8349, padded
#define PCW 4080                 // 8160 cells / 2 per word
#define DSLICE (HB * DCELLS)
#define PCSLICE (HB * PCW)

__device__ __forceinline__ int clampi(int v, int lo, int hi) {
    return v < lo ? lo : (v > hi ? hi : v);
}

__device__ __forceinline__ void tile_window(float x, float y, float r,
                                            int& x0, int& x1, int& y0, int& y1) {
    x0 = clampi((int)floorf((x - r) * 0.0625f), 0, NBW);
    x1 = clampi((int)floorf((x + r) * 0.0625f) + 1, 0, NBW);
    y0 = clampi((int)floorf((y - r) * 0.0625f), 0, NBH);
    y1 = clampi((int)floorf((y + r) * 0.0625f) + 1, 0, NBH);
}

// monotone float -> u32 such that ascending u32 == DESCENDING float
__device__ __forceinline__ u32 depth_key(float d) {
    u32 fu = __float_as_uint(d);
    u32 asc = (fu & 0x80000000u) ? ~fu : (fu | 0x80000000u);
    return ~asc;
}
__device__ __forceinline__ float depth_unkey(u32 dk) {
    u32 asc = ~dk;
    u32 fu = (asc & 0x80000000u) ? (asc & 0x7FFFFFFFu) : ~asc;
    return __uint_as_float(fu);
}

__device__ __forceinline__ int tile_of_block(int b) {
    return (b & 7) * (NTILES / 8) + (b >> 3);
}

// Exactly monotone (in dk) bucket map: table lookup on top-8 bits + integer
// linear interpolation. T is monotone non-decreasing, 0..NBKT.
__device__ __forceinline__ u32 bucket_of(u32 dk, const u32* __restrict__ Ts) {
    u32 k = dk >> 24;
    u32 t0 = Ts[k], t1 = Ts[k + 1];
    u32 b = t0 + (((t1 - t0) * ((dk >> 8) & 0xFFFFu)) >> 16);
    return b >= NBKT ? (NBKT - 1) : b;
}

__device__ __forceinline__ void lds_inc16(u32* arr, int cell) {
    atomicAdd(&arr[cell >> 1], (cell & 1) ? 0x10000u : 1u);
}

// 256 blocks x 512: LDS point-count histogram (packed u16) and LDS 2D
// difference-array corners (packed u16, plus/minus split). No pwin write.
__global__ __launch_bounds__(HT) void hist_kernel(const float2* __restrict__ pos,
                                                  const float* __restrict__ rad,
                                                  u32* __restrict__ pcslc,
                                                  int* __restrict__ diffslc) {
    __shared__ u32 s_pc[PCW];
    __shared__ u32 s_dp[DCELLS / 2];
    __shared__ u32 s_dm[DCELLS / 2];
    int tid = threadIdx.x;
    for (int w = tid; w < PCW; w += HT) s_pc[w] = 0;
    for (int w = tid; w < DCELLS / 2; w += HT) { s_dp[w] = 0; s_dm[w] = 0; }
    __syncthreads();

    for (int i = blockIdx.x * HT + tid; i < NPTS; i += HB * HT) {
        float2 p = pos[i];
        float r = rad[i];
        int x0, x1, y0, y1;
        tile_window(p.x, p.y, r, x0, x1, y0, y1);
        int cx = (int)(p.x * 0.0625f);
        int cy = (int)(p.y * 0.0625f);
        lds_inc16(s_pc, cx * NBH + cy);
        lds_inc16(s_dp, x0 * DY + y0);
        lds_inc16(s_dp, x1 * DY + y1);
        lds_inc16(s_dm, x0 * DY + y1);
        lds_inc16(s_dm, x1 * DY + y0);
    }
    __syncthreads();

    for (int w = tid; w < PCW; w += HT) pcslc[blockIdx.x * PCW + w] = s_pc[w];
    for (int c = tid; c < DCELLS; c += HT) {
        u32 pw = s_dp[c >> 1], mw = s_dm[c >> 1];
        int sh = (c & 1) * 16;
        diffslc[blockIdx.x * DCELLS + c] =
            (int)((pw >> sh) & 0xFFFFu) - (int)((mw >> sh) & 0xFFFFu);
    }
}

// Fused reduce + cursor table: per-tile totals (counts), per-(block,tile)
// exclusive prefix (ctab0, WITHOUT po), and diff reduction (sdg).
__global__ void reduce_kernel(const u32* __restrict__ pcslc, const int* __restrict__ diffslc,
                              u32* __restrict__ counts, u32* __restrict__ ctab0,
                              int* __restrict__ sdg) {
    int idx = blockIdx.x * 256 + threadIdx.x;
    if (idx < NTILES) {
        int sh = (idx & 1) * 16;
        int w = idx >> 1;
        u32 run = 0;
        for (int b = 0; b < HB; ++b) {
            ctab0[b * NTILES + idx] = run;
            run += (pcslc[b * PCW + w] >> sh) & 0xFFFFu;
        }
        counts[idx] = run;
    } else if (idx < NTILES + DCELLS) {
        int c = idx - NTILES;
        int acc = 0;
        for (int b = 0; b < HB; ++b) acc += diffslc[b * DCELLS + c];
        sdg[c] = acc;
    }
}

// 3 parallel blocks: 0 = point-count scan -> po; 1 = diff 2D prefix + entry
// scan -> eo + out_count; 2 = bucket table -> Tg.
__global__ __launch_bounds__(1024) void scan3_kernel(const u32* __restrict__ counts,
                                                     u32* __restrict__ po,
                                                     const int* __restrict__ sdg,
                                                     u32* __restrict__ eo,
                                                     float* __restrict__ out_count,
                                                     u32* __restrict__ Tg) {
    __shared__ u32 sA[1024], sB[1024];
    __shared__ int sd[DCELLS];
    __shared__ u32 traw[257];
    int t = threadIdx.x;
    int base = t * 8;

    if (blockIdx.x == 0) {
        // ---- point-count scan -> po ----
        u32 local[8]; u32 sum = 0;
#pragma unroll
        for (int j = 0; j < 8; ++j) {
            u32 c = (base + j < NTILES) ? counts[base + j] : 0u;
            local[j] = c; sum += c;
        }
        sA[t] = sum;
        __syncthreads();
        u32 *cur = sA, *nxt = sB;
        for (int off = 1; off < 1024; off <<= 1) {
            u32 v = cur[t];
            if (t >= off) v += cur[t - off];
            nxt[t] = v;
            __syncthreads();
            u32* tmp = cur; cur = nxt; nxt = tmp;
        }
        u32 run = cur[t] - sum;
#pragma unroll
        for (int j = 0; j < 8; ++j) {
            int idx = base + j;
            if (idx < NTILES) { po[idx] = run; run += local[j]; }
        }
        if (t == 1023) po[NTILES] = cur[1023];
    } else if (blockIdx.x == 1) {
        // ---- 2D prefix of diff array -> entry counts -> scan ----
        for (int c = t; c < DCELLS; c += 1024) sd[c] = sdg[c];
        __syncthreads();
        if (t < DX) { int run = 0; for (int y = 0; y < DY; ++y) { run += sd[t * DY + y]; sd[t * DY + y] = run; } }
        __syncthreads();
        if (t < DY) { int run = 0; for (int x = 0; x < DX; ++x) { run += sd[x * DY + t]; sd[x * DY + t] = run; } }
        __syncthreads();

        u32 local[8]; u32 sum = 0;
#pragma unroll
        for (int j = 0; j < 8; ++j) {
            int idx = base + j;
            u32 c = 0;
            if (idx < NTILES) {
                int x = idx / NBH, y = idx % NBH;
                c = (u32)sd[x * DY + y];
            }
            local[j] = c; sum += c;
        }
        sA[t] = sum;
        __syncthreads();
        u32 *cur = sA, *nxt = sB;
        for (int off = 1; off < 1024; off <<= 1) {
            u32 v = cur[t];
            if (t >= off) v += cur[t - off];
            nxt[t] = v;
            __syncthreads();
            u32* tmp = cur; cur = nxt; nxt = tmp;
        }
        u32 run = cur[t] - sum;
#pragma unroll
        for (int j = 0; j < 8; ++j) {
            int idx = base + j;
            if (idx < NTILES) {
                eo[idx] = run;
                out_count[idx] = (float)run;
                run += local[j];
            }
        }
        if (t == 1023) eo[NTILES] = cur[1023];
    } else {
        // ---- bucket table from normal CDF; monotone by running max ----
        if (t < 257) {
            u32 dkb = (u32)t << 24;
            float d = depth_unkey(dkb);
            float u;
            if (d != d) u = (t < 128) ? 0.f : 1.f;
            else {
                float dc = fminf(fmaxf(d, -12.f), 12.f);
                u = 0.5f * erfcf(dc * 0.70710678f);
            }
            traw[t] = (u32)(u * (float)NBKT + 0.5f);
        }
        __syncthreads();
        if (t == 0) {
            u32 run = 0;
            for (int k = 0; k < 257; ++k) {
                u32 v = traw[k];
                if (v > NBKT) v = NBKT;
                if (v > run) run = v;
                Tg[k] = run;
            }
        }
    }
}

// Same block<->point mapping as hist; cursors = ctab0 row + po in LDS.
// Recomputes window/ct/key from pos/rad/depth (coalesced reads). Writes 16B
// records {key=(dk<<19)|pid, window} in center-sorted order. LDS atomics only.
__global__ __launch_bounds__(HT) void point_scatter_kernel(const float2* __restrict__ pos,
                                                           const float* __restrict__ rad,
                                                           const float* __restrict__ depth,
                                                           const u32* __restrict__ ctab0,
                                                           const u32* __restrict__ po,
                                                           ulonglong2* __restrict__ pe16) {
    __shared__ u32 cur[NTILES];
    int tid = threadIdx.x;
    for (int w = tid; w < NTILES; w += HT)
        cur[w] = ctab0[blockIdx.x * NTILES + w] + po[w];
    __syncthreads();
    for (int i = blockIdx.x * HT + tid; i < NPTS; i += HB * HT) {
        float2 p = pos[i];
        float r = rad[i];
        int x0, x1, y0, y1;
        tile_window(p.x, p.y, r, x0, x1, y0, y1);
        int cx = (int)(p.x * 0.0625f);
        int cy = (int)(p.y * 0.0625f);
        u32 dk = depth_key(depth[i]);
        u32 w = (u32)x0 | ((u32)y0 << 7) | ((u32)x1 << 14) | ((u32)y1 << 21);
        u32 slot = atomicAdd(&cur[cx * NBH + cy], 1u);
        pe16[slot] = make_ulonglong2(((u64)dk << 19) | (u64)(u32)i, (u64)w);
    }
}

// One block per tile: tail-fill slice + two coalesced candidate passes over
// 16B records (no dependent gathers) into 1024 depth-CDF buckets +
// per-thread insertion sort per bucket + coalesced write.   [R6-verified]
__global__ __launch_bounds__(256) void tile_build_kernel(const u32* __restrict__ po,
                                                         const ulonglong2* __restrict__ pe16,
                                                         const u32* __restrict__ eo,
                                                         const u32* __restrict__ Tg,
                                                         float* __restrict__ out_idx,
                                                         float* __restrict__ out_depth) {
    __shared__ u64 keys[SORT_CAP];          // 16 KB
    __shared__ u32 boff[NBKT + 1];
    __shared__ u32 bcur[NBKT];
    __shared__ u32 Ts[257];
    __shared__ u32 wsum[4];
    __shared__ u32 lcnt;

    int tid = threadIdx.x;
    int lane = tid & 63;
    int wv = tid >> 6;

    // ---- fused tail fill: pad [total, EE) with -1 / 0 ----
    {
        u32 total = eo[NTILES];
        u32 tailn = EE - total;
        u32 per = (tailn + NTILES - 1) / NTILES;
        u64 s = (u64)total + (u64)blockIdx.x * per;
        u64 e = s + per; if (e > (u64)EE) e = EE;
        for (u64 i = s + tid; i < e; i += 256) {
            out_idx[i] = -1.f;
            out_depth[i] = 0.f;
        }
    }

    int t = tile_of_block(blockIdx.x);
    u32 base = eo[t];
    int cnt = (int)(eo[t + 1] - base);
    if (cnt <= 0) return;

    int tx = t / NBH;
    int ty = t % NBH;
    bool big = cnt > SORT_CAP;

    for (int b = tid; b < NBKT; b += 256) boff[b] = 0;
    for (int k = tid; k < 257; k += 256) Ts[k] = Tg[k];
    if (tid == 0) lcnt = 0;
    __syncthreads();

    int cx0 = tx - 2 < 0 ? 0 : tx - 2;
    int cx1 = tx + 2 > NBW - 1 ? NBW - 1 : tx + 2;
    int cy0 = ty - 2 < 0 ? 0 : ty - 2;
    int cy1 = ty + 2 > NBH - 1 ? NBH - 1 : ty + 2;

    if (!big) {
        // ---- pass 1: bucket histogram ----
        for (int cx = cx0; cx <= cx1; ++cx) {
            u32 s = po[cx * NBH + cy0];
            u32 e = po[cx * NBH + cy1 + 1];
            for (u32 i = s + tid; i < e; i += 256) {
                ulonglong2 en = pe16[i];
                u32 w = (u32)en.y;
                int x0 = (int)(w & 127u), y0 = (int)((w >> 7) & 127u);
                int x1 = (int)((w >> 14) & 127u), y1 = (int)((w >> 21) & 127u);
                if (tx >= x0 && tx < x1 && ty >= y0 && ty < y1) {
                    u32 dk = (u32)(en.x >> 19);
                    atomicAdd(&boff[bucket_of(dk, Ts)], 1u);
                }
            }
        }
        __syncthreads();

        // ---- exclusive scan of 1024 buckets ----
        {
            int b0 = tid * 4;
            u32 h0 = boff[b0], h1 = boff[b0 + 1], h2 = boff[b0 + 2], h3 = boff[b0 + 3];
            u32 tsum = h0 + h1 + h2 + h3;
            u32 v = tsum;
            for (int off = 1; off < 64; off <<= 1) {
                u32 n = __shfl_up(v, off, 64);
                if (lane >= off) v += n;
            }
            if (lane == 63) wsum[wv] = v;
            __syncthreads();
            u32 wpre = 0;
            for (int w = 0; w < wv; ++w) wpre += wsum[w];
            u32 run = wpre + v - tsum;
            boff[b0] = run;     bcur[b0] = run;     run += h0;
            boff[b0 + 1] = run; bcur[b0 + 1] = run; run += h1;
            boff[b0 + 2] = run; bcur[b0 + 2] = run; run += h2;
            boff[b0 + 3] = run; bcur[b0 + 3] = run; run += h3;
            if (tid == 255) boff[NBKT] = run;
        }
        __syncthreads();

        // ---- pass 2: scatter keys into bucketed order ----
        for (int cx = cx0; cx <= cx1; ++cx) {
            u32 s = po[cx * NBH + cy0];
            u32 e = po[cx * NBH + cy1 + 1];
            for (u32 i = s + tid; i < e; i += 256) {
                ulonglong2 en = pe16[i];
                u32 w = (u32)en.y;
                int x0 = (int)(w & 127u), y0 = (int)((w >> 7) & 127u);
                int x1 = (int)((w >> 14) & 127u), y1 = (int)((w >> 21) & 127u);
                if (tx >= x0 && tx < x1 && ty >= y0 && ty < y1) {
                    u32 dk = (u32)(en.x >> 19);
                    u32 slot = atomicAdd(&bcur[bucket_of(dk, Ts)], 1u);
                    keys[slot] = en.x;
                }
            }
        }
        __syncthreads();

        // ---- per-thread insertion sort of each bucket ----
        for (int b = tid; b < NBKT; b += 256) {
            int s = (int)boff[b], e = (int)boff[b + 1];
            for (int i = s + 1; i < e; ++i) {
                u64 k = keys[i];
                int j = i - 1;
                while (j >= s && keys[j] > k) { keys[j + 1] = keys[j]; --j; }
                keys[j + 1] = k;
            }
        }
        __syncthreads();

        // ---- decode + coalesced write ----
        for (int i = tid; i < cnt; i += 256) {
            u64 k = keys[i];
            u32 pid = (u32)(k & 0x7FFFFu);
            u32 dk  = (u32)(k >> 19);
            out_idx[base + i]   = (float)pid;
            out_depth[base + i] = depth_unkey(dk);
        }
    } else {
        // Statistically unreachable fallback: append to global, odd-even sort.
        for (int cx = cx0; cx <= cx1; ++cx) {
            u32 s = po[cx * NBH + cy0];
            u32 e = po[cx * NBH + cy1 + 1];
            for (u32 i = s + tid; i < e; i += 256) {
                ulonglong2 en = pe16[i];
                u32 w = (u32)en.y;
                int x0 = (int)(w & 127u), y0 = (int)((w >> 7) & 127u);
                int x1 = (int)((w >> 14) & 127u), y1 = (int)((w >> 21) & 127u);
                if (tx >= x0 && tx < x1 && ty >= y0 && ty < y1) {
                    u32 pid = (u32)(en.x & 0x7FFFFu);
                    u32 dk  = (u32)(en.x >> 19);
                    u32 slot = atomicAdd(&lcnt, 1u);
                    out_idx[base + slot] = (float)pid;
                    out_depth[base + slot] = depth_unkey(dk);
                }
            }
        }
        __syncthreads();
        for (int round = 0; round < cnt; ++round) {
            for (int i = (round & 1) + 2 * tid; i + 1 < cnt; i += 512) {
                float fi0 = out_idx[base + i], fi1 = out_idx[base + i + 1];
                float fd0 = out_depth[base + i], fd1 = out_depth[base + i + 1];
                u64 k0 = ((u64)depth_key(fd0) << 19) | (u64)(u32)fi0;
                u64 k1 = ((u64)depth_key(fd1) << 19) | (u64)(u32)fi1;
                if (k0 > k1) {
                    out_idx[base + i] = fi1; out_idx[base + i + 1] = fi0;
                    out_depth[base + i] = fd1; out_depth[base + i + 1] = fd0;
                }
            }
            __syncthreads();
        }
    }
}

extern "C" void kernel_launch(void* const* d_in, const int* in_sizes, int n_in,
                              void* d_out, int out_size, void* d_ws, size_t ws_size,
                              hipStream_t stream) {
    (void)in_sizes; (void)n_in; (void)out_size; (void)ws_size;

    const float2* pos  = (const float2*)d_in[0];
    const float* rad   = (const float*)d_in[1];
    const float* depth = (const float*)d_in[2];

    float* out        = (float*)d_out;
    float* out_count  = out;                 // [NTILES]
    float* out_idx    = out + NTILES;        // [EE]
    float* out_depth  = out + NTILES + EE;   // [EE]

    // ws layout (~8.1 MB): 16B records first, then u32 arrays
    ulonglong2* pe16 = (ulonglong2*)d_ws;    // [NPTS] {key, window}
    u32* counts = (u32*)(pe16 + NPTS);       // [NTILES]
    u32* po     = counts + NTILES;           // [NTILES+1]
    u32* eo     = po + NTILES + 1;           // [NTILES+1]
    int* sdg    = (int*)(eo + NTILES + 1);   // [DCELLS]
    u32* Tg     = (u32*)(sdg + DCELLS);      // [257]

    // Large staging lives in the guaranteed-dead output tail (total entries
    // <= 8M of 12.5M since radius < 24 -> window <= 4x4).
    // ctab0 (8.4 MB) in out_idx tail; pcslc+diffslc (12.7 MB) in out_depth tail.
    u32* ctab0   = (u32*)out_idx + (EE - HB * NTILES);
    u32* pcslc   = (u32*)(out_depth + EE) - (PCSLICE + DSLICE);
    int* diffslc = (int*)(pcslc + PCSLICE);

    hist_kernel<<<HB, HT, 0, stream>>>(pos, rad, pcslc, diffslc);
    reduce_kernel<<<(NTILES + DCELLS + 255) / 256, 256, 0, stream>>>(pcslc, diffslc,
                                                                     counts, ctab0, sdg);
    scan3_kernel<<<3, 1024, 0, stream>>>(counts, po, sdg, eo, out_count, Tg);
    point_scatter_kernel<<<HB, HT, 0, stream>>>(pos, rad, depth, ctab0, po, pe16);
    tile_build_kernel<<<NTILES, 256, 0, stream>>>(po, pe16, eo, Tg,
                                                  out_idx, out_depth);
}